// Round 1
// baseline (2863.961 us; speedup 1.0000x reference)
//
#include <hip/hip_runtime.h>
#include <hip/hip_bf16.h>

typedef __bf16 bf16_t;
typedef __attribute__((ext_vector_type(8))) __bf16 bf16x8;
typedef __attribute__((ext_vector_type(4))) __bf16 bf16x4;
typedef __attribute__((ext_vector_type(4))) float f32x4;

#define LDS_STRIDE 40   // bf16 elems per row (128-row tiles, 32 k); 80B rows -> 2 lanes/bank on b128 reads

// C[M][N] = A[M][K] @ B[N][K]^T, all fp32 row-major. Internally bf16 hi/lo MFMA (3-pass compensation).
__global__ __launch_bounds__(256) void gemm_hilo(const float* __restrict__ A,
                                                 const float* __restrict__ B,
                                                 float* __restrict__ C,
                                                 int M, int N, int K)
{
    __shared__ bf16_t sAh[128 * LDS_STRIDE];
    __shared__ bf16_t sAl[128 * LDS_STRIDE];
    __shared__ bf16_t sBh[128 * LDS_STRIDE];
    __shared__ bf16_t sBl[128 * LDS_STRIDE];

    const int tid  = threadIdx.x;
    const int lane = tid & 63;
    const int wave = tid >> 6;          // 0..3
    const int wr   = (wave >> 1) * 64;  // wave row offset in tile
    const int wc   = (wave & 1) * 64;   // wave col offset in tile
    const int row0 = blockIdx.y * 128;
    const int col0 = blockIdx.x * 128;

    f32x4 acc[4][4] = {};

    const int lrow = tid >> 3;        // 0..31
    const int lcol = (tid & 7) * 4;   // 0,4,..,28

    for (int kt = 0; kt < K; kt += 32) {
        // ---- stage A,B tiles: fp32 -> (hi, lo) bf16 ----
        #pragma unroll
        for (int p = 0; p < 4; ++p) {
            const int row = p * 32 + lrow;
            const float4 va = *reinterpret_cast<const float4*>(&A[(size_t)(row0 + row) * K + kt + lcol]);
            const float4 vb = *reinterpret_cast<const float4*>(&B[(size_t)(col0 + row) * K + kt + lcol]);
            float fa[4] = {va.x, va.y, va.z, va.w};
            float fb[4] = {vb.x, vb.y, vb.z, vb.w};
            bf16x4 ah, al, bh, bl;
            #pragma unroll
            for (int e = 0; e < 4; ++e) {
                bf16_t h = (bf16_t)fa[e];
                ah[e] = h;
                al[e] = (bf16_t)(fa[e] - (float)h);
                bf16_t g = (bf16_t)fb[e];
                bh[e] = g;
                bl[e] = (bf16_t)(fb[e] - (float)g);
            }
            *reinterpret_cast<bf16x4*>(&sAh[row * LDS_STRIDE + lcol]) = ah;
            *reinterpret_cast<bf16x4*>(&sAl[row * LDS_STRIDE + lcol]) = al;
            *reinterpret_cast<bf16x4*>(&sBh[row * LDS_STRIDE + lcol]) = bh;
            *reinterpret_cast<bf16x4*>(&sBl[row * LDS_STRIDE + lcol]) = bl;
        }
        __syncthreads();

        // ---- fragments ----
        const int fr = lane & 15;
        const int kc = (lane >> 4) * 8;
        bf16x8 fah[4], fal[4], fbh[4], fbl[4];
        #pragma unroll
        for (int i = 0; i < 4; ++i) {
            const int ar = wr + i * 16 + fr;
            fah[i] = *reinterpret_cast<const bf16x8*>(&sAh[ar * LDS_STRIDE + kc]);
            fal[i] = *reinterpret_cast<const bf16x8*>(&sAl[ar * LDS_STRIDE + kc]);
            const int br = wc + i * 16 + fr;
            fbh[i] = *reinterpret_cast<const bf16x8*>(&sBh[br * LDS_STRIDE + kc]);
            fbl[i] = *reinterpret_cast<const bf16x8*>(&sBl[br * LDS_STRIDE + kc]);
        }

        #pragma unroll
        for (int i = 0; i < 4; ++i)
            #pragma unroll
            for (int j = 0; j < 4; ++j) {
                acc[i][j] = __builtin_amdgcn_mfma_f32_16x16x32_bf16(fah[i], fbh[j], acc[i][j], 0, 0, 0);
                acc[i][j] = __builtin_amdgcn_mfma_f32_16x16x32_bf16(fal[i], fbh[j], acc[i][j], 0, 0, 0);
                acc[i][j] = __builtin_amdgcn_mfma_f32_16x16x32_bf16(fah[i], fbl[j], acc[i][j], 0, 0, 0);
            }
        __syncthreads();
    }

    // ---- epilogue: C/D layout col=lane&15, row=(lane>>4)*4+reg ----
    const int crow = row0 + wr + (lane >> 4) * 4;
    const int ccol = col0 + wc + (lane & 15);
    #pragma unroll
    for (int i = 0; i < 4; ++i)
        #pragma unroll
        for (int j = 0; j < 4; ++j)
            #pragma unroll
            for (int rr = 0; rr < 4; ++rr)
                C[(size_t)(crow + i * 16 + rr) * N + ccol + j * 16] = acc[i][j][rr];
}

// In-place RoPE on xq (2048,32,128) and xk (2048,8,128); interleaved pairs, cos/sin per (s, j=d/2).
__global__ __launch_bounds__(256) void rope_k(float* __restrict__ xq, float* __restrict__ xk)
{
    const int idx = blockIdx.x * 256 + threadIdx.x;
    const int TOTQ = 2048 * 32 * 64;   // q pairs
    int s, j;
    float* base;
    if (idx < TOTQ) {
        s = idx >> 11;                 // / (32*64)
        const int rem = idx & 2047;
        j = rem & 63;
        base = xq + (size_t)s * 4096 + (rem >> 6) * 128 + 2 * j;
    } else {
        const int i2 = idx - TOTQ;     // < 2048*8*64
        s = i2 >> 9;                   // / (8*64)
        const int rem = i2 & 511;
        j = rem & 63;
        base = xk + (size_t)s * 1024 + (rem >> 6) * 128 + 2 * j;
    }
    // inv_freq = 10000^(-2j/128) = exp2(-j/64 * log2(10000))
    const float invf = exp2f(-(float)j * (13.287712379549449f / 64.0f));
    const float ang = (float)s * invf;
    float sn, cs;
    sincosf(ang, &sn, &cs);
    float2 v = *reinterpret_cast<float2*>(base);
    float2 r;
    r.x = v.x * cs - v.y * sn;
    r.y = v.x * sn + v.y * cs;
    *reinterpret_cast<float2*>(base) = r;
}

// fp32 flash attention (non-causal, GQA 32q/8kv heads, hd=128, S=2048).
// Block: (q-tile of 32 rows, head). 256 threads = 32 rows x 8 parts; part owns dims {part + 8*j}.
__global__ __launch_bounds__(256) void attn_fp32(const float* __restrict__ xq,
                                                 const float* __restrict__ xk,
                                                 const float* __restrict__ xv,
                                                 float* __restrict__ ao)
{
    __shared__ float Qs[32][132];
    __shared__ float Ks[32][132];
    __shared__ float Vs[32][132];
    __shared__ float Ps[32][36];

    const int h   = blockIdx.y;
    const int q0  = blockIdx.x * 32;
    const int hkv = h >> 2;
    const int tid = threadIdx.x;
    const int r    = tid >> 3;
    const int part = tid & 7;

    #pragma unroll
    for (int ii = 0; ii < 4; ++ii) {
        const int fi = ii * 256 + tid;       // float4 index 0..1023
        const int row = fi >> 5;
        const int c4  = (fi & 31) * 4;
        *reinterpret_cast<float4*>(&Qs[row][c4]) =
            *reinterpret_cast<const float4*>(&xq[(size_t)(q0 + row) * 4096 + h * 128 + c4]);
    }

    float o[16];
    #pragma unroll
    for (int jj = 0; jj < 16; ++jj) o[jj] = 0.f;
    float m = -3.0e38f, l = 0.f;

    for (int kt = 0; kt < 2048; kt += 32) {
        __syncthreads();   // prior PV reads of Vs done
        #pragma unroll
        for (int ii = 0; ii < 4; ++ii) {
            const int fi = ii * 256 + tid;
            const int row = fi >> 5;
            const int c4  = (fi & 31) * 4;
            *reinterpret_cast<float4*>(&Ks[row][c4]) =
                *reinterpret_cast<const float4*>(&xk[(size_t)(kt + row) * 1024 + hkv * 128 + c4]);
            *reinterpret_cast<float4*>(&Vs[row][c4]) =
                *reinterpret_cast<const float4*>(&xv[(size_t)(kt + row) * 1024 + hkv * 128 + c4]);
        }
        __syncthreads();

        float s0 = 0.f, s1 = 0.f, s2 = 0.f, s3 = 0.f;
        #pragma unroll 8
        for (int d = 0; d < 128; ++d) {
            const float q = Qs[r][d];
            s0 += q * Ks[part][d];
            s1 += q * Ks[part + 8][d];
            s2 += q * Ks[part + 16][d];
            s3 += q * Ks[part + 24][d];
        }
        const float scale = 0.08838834764831845f;  // 1/sqrt(128)
        s0 *= scale; s1 *= scale; s2 *= scale; s3 *= scale;

        float mx = fmaxf(fmaxf(s0, s1), fmaxf(s2, s3));
        mx = fmaxf(mx, __shfl_xor(mx, 1));
        mx = fmaxf(mx, __shfl_xor(mx, 2));
        mx = fmaxf(mx, __shfl_xor(mx, 4));
        const float mnew = fmaxf(m, mx);

        const float p0 = __expf(s0 - mnew);
        const float p1 = __expf(s1 - mnew);
        const float p2 = __expf(s2 - mnew);
        const float p3 = __expf(s3 - mnew);
        float ps = p0 + p1 + p2 + p3;
        ps += __shfl_xor(ps, 1);
        ps += __shfl_xor(ps, 2);
        ps += __shfl_xor(ps, 4);

        const float corr = __expf(m - mnew);
        l = l * corr + ps;
        m = mnew;

        Ps[r][part]      = p0;
        Ps[r][part + 8]  = p1;
        Ps[r][part + 16] = p2;
        Ps[r][part + 24] = p3;
        #pragma unroll
        for (int jj = 0; jj < 16; ++jj) o[jj] *= corr;
        __syncthreads();

        #pragma unroll 4
        for (int c = 0; c < 32; ++c) {
            const float pc = Ps[r][c];
            #pragma unroll
            for (int jj = 0; jj < 16; ++jj)
                o[jj] += pc * Vs[c][part + 8 * jj];
        }
    }

    const float inv_l = 1.0f / l;
    #pragma unroll
    for (int jj = 0; jj < 16; ++jj)
        ao[(size_t)(q0 + r) * 4096 + h * 128 + part + 8 * jj] = o[jj] * inv_l;
}

extern "C" void kernel_launch(void* const* d_in, const int* in_sizes, int n_in,
                              void* d_out, int out_size, void* d_ws, size_t ws_size,
                              hipStream_t stream)
{
    const float* x  = (const float*)d_in[0];
    const float* wq = (const float*)d_in[1];
    const float* wk = (const float*)d_in[2];
    const float* wv = (const float*)d_in[3];
    const float* wo = (const float*)d_in[4];
    float* out = (float*)d_out;

    float* ws = (float*)d_ws;
    float* xq = ws;                   // 2048*4096
    float* xk = ws + 8388608;         // 2048*1024
    float* xv = ws + 10485760;        // 2048*1024
    float* ao = ws + 12582912;        // 2048*4096  (total 83.9 MB)

    dim3 blk(256);
    gemm_hilo<<<dim3(32, 16), blk, 0, stream>>>(x, wq, xq, 2048, 4096, 4096);
    gemm_hilo<<<dim3(8, 16),  blk, 0, stream>>>(x, wk, xk, 2048, 1024, 4096);
    gemm_hilo<<<dim3(8, 16),  blk, 0, stream>>>(x, wv, xv, 2048, 1024, 4096);
    rope_k<<<dim3(20480), blk, 0, stream>>>(xq, xk);
    attn_fp32<<<dim3(64, 32), blk, 0, stream>>>(xq, xk, xv, ao);
    gemm_hilo<<<dim3(32, 16), blk, 0, stream>>>(ao, wo, out, 2048, 4096, 4096);
}

// Round 2
// 1128.058 us; speedup vs baseline: 2.5388x; 2.5388x over previous
//
#include <hip/hip_runtime.h>
#include <hip/hip_bf16.h>

typedef __bf16 bf16_t;
typedef unsigned int uint;
typedef __attribute__((ext_vector_type(8))) __bf16 bf16x8;
typedef __attribute__((ext_vector_type(4))) __bf16 bf16x4;
typedef __attribute__((ext_vector_type(4))) float f32x4;
typedef __attribute__((ext_vector_type(16))) float f32x16;

#define LDS_STRIDE 40

// ---------------- GEMM (unchanged, proven): C[M][N] = A @ B^T, fp32 via bf16 hi/lo 3-pass ----------------
__global__ __launch_bounds__(256) void gemm_hilo(const float* __restrict__ A,
                                                 const float* __restrict__ B,
                                                 float* __restrict__ C,
                                                 int M, int N, int K)
{
    __shared__ bf16_t sAh[128 * LDS_STRIDE];
    __shared__ bf16_t sAl[128 * LDS_STRIDE];
    __shared__ bf16_t sBh[128 * LDS_STRIDE];
    __shared__ bf16_t sBl[128 * LDS_STRIDE];

    const int tid  = threadIdx.x;
    const int lane = tid & 63;
    const int wave = tid >> 6;
    const int wr   = (wave >> 1) * 64;
    const int wc   = (wave & 1) * 64;
    const int row0 = blockIdx.y * 128;
    const int col0 = blockIdx.x * 128;

    f32x4 acc[4][4] = {};

    const int lrow = tid >> 3;
    const int lcol = (tid & 7) * 4;

    for (int kt = 0; kt < K; kt += 32) {
        #pragma unroll
        for (int p = 0; p < 4; ++p) {
            const int row = p * 32 + lrow;
            const float4 va = *reinterpret_cast<const float4*>(&A[(size_t)(row0 + row) * K + kt + lcol]);
            const float4 vb = *reinterpret_cast<const float4*>(&B[(size_t)(col0 + row) * K + kt + lcol]);
            float fa[4] = {va.x, va.y, va.z, va.w};
            float fb[4] = {vb.x, vb.y, vb.z, vb.w};
            bf16x4 ah, al, bh, bl;
            #pragma unroll
            for (int e = 0; e < 4; ++e) {
                bf16_t hv = (bf16_t)fa[e];
                ah[e] = hv;
                al[e] = (bf16_t)(fa[e] - (float)hv);
                bf16_t g = (bf16_t)fb[e];
                bh[e] = g;
                bl[e] = (bf16_t)(fb[e] - (float)g);
            }
            *reinterpret_cast<bf16x4*>(&sAh[row * LDS_STRIDE + lcol]) = ah;
            *reinterpret_cast<bf16x4*>(&sAl[row * LDS_STRIDE + lcol]) = al;
            *reinterpret_cast<bf16x4*>(&sBh[row * LDS_STRIDE + lcol]) = bh;
            *reinterpret_cast<bf16x4*>(&sBl[row * LDS_STRIDE + lcol]) = bl;
        }
        __syncthreads();

        const int fr = lane & 15;
        const int kc = (lane >> 4) * 8;
        bf16x8 fah[4], fal[4], fbh[4], fbl[4];
        #pragma unroll
        for (int i = 0; i < 4; ++i) {
            const int ar = wr + i * 16 + fr;
            fah[i] = *reinterpret_cast<const bf16x8*>(&sAh[ar * LDS_STRIDE + kc]);
            fal[i] = *reinterpret_cast<const bf16x8*>(&sAl[ar * LDS_STRIDE + kc]);
            const int br = wc + i * 16 + fr;
            fbh[i] = *reinterpret_cast<const bf16x8*>(&sBh[br * LDS_STRIDE + kc]);
            fbl[i] = *reinterpret_cast<const bf16x8*>(&sBl[br * LDS_STRIDE + kc]);
        }

        #pragma unroll
        for (int i = 0; i < 4; ++i)
            #pragma unroll
            for (int j = 0; j < 4; ++j) {
                acc[i][j] = __builtin_amdgcn_mfma_f32_16x16x32_bf16(fah[i], fbh[j], acc[i][j], 0, 0, 0);
                acc[i][j] = __builtin_amdgcn_mfma_f32_16x16x32_bf16(fal[i], fbh[j], acc[i][j], 0, 0, 0);
                acc[i][j] = __builtin_amdgcn_mfma_f32_16x16x32_bf16(fah[i], fbl[j], acc[i][j], 0, 0, 0);
            }
        __syncthreads();
    }

    const int crow = row0 + wr + (lane >> 4) * 4;
    const int ccol = col0 + wc + (lane & 15);
    #pragma unroll
    for (int i = 0; i < 4; ++i)
        #pragma unroll
        for (int j = 0; j < 4; ++j)
            #pragma unroll
            for (int rr = 0; rr < 4; ++rr)
                C[(size_t)(crow + i * 16 + rr) * N + ccol + j * 16] = acc[i][j][rr];
}

// ---------------- RoPE in place; Q additionally scaled by 1/sqrt(128) ----------------
__global__ __launch_bounds__(256) void rope_k(float* __restrict__ xq, float* __restrict__ xk)
{
    const int idx = blockIdx.x * 256 + threadIdx.x;
    const int TOTQ = 2048 * 32 * 64;
    int s, j;
    float* base;
    bool isq = idx < TOTQ;
    if (isq) {
        s = idx >> 11;
        const int rem = idx & 2047;
        j = rem & 63;
        base = xq + (size_t)s * 4096 + (rem >> 6) * 128 + 2 * j;
    } else {
        const int i2 = idx - TOTQ;
        s = i2 >> 9;
        const int rem = i2 & 511;
        j = rem & 63;
        base = xk + (size_t)s * 1024 + (rem >> 6) * 128 + 2 * j;
    }
    const float invf = exp2f(-(float)j * (13.287712379549449f / 64.0f));
    const float ang = (float)s * invf;
    float sn, cs;
    sincosf(ang, &sn, &cs);
    float2 v = *reinterpret_cast<float2*>(base);
    float2 r;
    r.x = v.x * cs - v.y * sn;
    r.y = v.x * sn + v.y * cs;
    if (isq) { r.x *= 0.08838834764831845f; r.y *= 0.08838834764831845f; }
    *reinterpret_cast<float2*>(base) = r;
}

// ---------------- Convert roped K and raw V to blocked+swizzled bf16 hi/lo tiles ----------------
// KVg layout: [h(8)][t(64)] tiles of 16384 uint16 elems (32 KB):
//   Kh [32 kv][128 d] at 0     : elem = r*128 + ((d>>3)^(r&15))*8 + (d&7)
//   Kl at 4096
//   Vth [128 d][32 kv] at 8192 : elem = d*32 + ((k>>3)^(d&3))*8 + (k&7)
//   Vtl at 12288
__global__ __launch_bounds__(256) void conv_kv(const float* __restrict__ xk,
                                               const float* __restrict__ xv,
                                               uint16_t* __restrict__ kvg)
{
    __shared__ float V[32][129];
    const int t = blockIdx.x;
    const int h = blockIdx.y;
    const int tid = threadIdx.x;
    uint16_t* tile = kvg + ((size_t)(h * 64 + t)) * 16384;

    // stage V tile (32 kv rows x 128 d) into LDS
    #pragma unroll
    for (int i = 0; i < 4; ++i) {
        int v = i * 256 + tid;
        int row = v >> 5, c4 = (v & 31) * 4;
        *reinterpret_cast<float4*>(&V[row][c4]) =
            *reinterpret_cast<const float4*>(&xv[(size_t)(t * 32 + row) * 1024 + h * 128 + c4]);
    }

    // K: direct (no transpose). thread -> (row r, 16 d starting at d0)
    {
        const int r = tid >> 3;
        const int d0 = (tid & 7) * 16;
        float f[16];
        const float* kr = &xk[(size_t)(t * 32 + r) * 1024 + h * 128 + d0];
        *reinterpret_cast<float4*>(&f[0])  = *reinterpret_cast<const float4*>(kr);
        *reinterpret_cast<float4*>(&f[4])  = *reinterpret_cast<const float4*>(kr + 4);
        *reinterpret_cast<float4*>(&f[8])  = *reinterpret_cast<const float4*>(kr + 8);
        *reinterpret_cast<float4*>(&f[12]) = *reinterpret_cast<const float4*>(kr + 12);
        #pragma unroll
        for (int cc = 0; cc < 2; ++cc) {
            bf16x8 hv, lv;
            #pragma unroll
            for (int e = 0; e < 8; ++e) {
                float x = f[cc * 8 + e];
                bf16_t hb = (bf16_t)x;
                hv[e] = hb;
                lv[e] = (bf16_t)(x - (float)hb);
            }
            const int c = (d0 >> 3) + cc;
            const int pos = r * 128 + ((c ^ (r & 15)) << 3);
            *reinterpret_cast<bf16x8*>(&tile[pos]) = hv;
            *reinterpret_cast<bf16x8*>(&tile[4096 + pos]) = lv;
        }
    }
    __syncthreads();
    // V: transposed. thread -> (d row, 16 kv starting at k0)
    {
        const int d = tid >> 1;
        const int k0 = (tid & 1) * 16;
        float g[16];
        #pragma unroll
        for (int j = 0; j < 16; ++j) g[j] = V[k0 + j][d];
        #pragma unroll
        for (int cc = 0; cc < 2; ++cc) {
            bf16x8 hv, lv;
            #pragma unroll
            for (int e = 0; e < 8; ++e) {
                float x = g[cc * 8 + e];
                bf16_t hb = (bf16_t)x;
                hv[e] = hb;
                lv[e] = (bf16_t)(x - (float)hb);
            }
            const int c = (k0 >> 3) + cc;
            const int pos = d * 32 + ((c ^ (d & 3)) << 3);
            *reinterpret_cast<bf16x8*>(&tile[8192 + pos]) = hv;
            *reinterpret_cast<bf16x8*>(&tile[12288 + pos]) = lv;
        }
    }
}

// ---------------- MFMA flash attention ----------------
__device__ __forceinline__ uint cvtpk(float lo, float hi) {
    uint r;
    asm("v_cvt_pk_bf16_f32 %0, %1, %2" : "=v"(r) : "v"(lo), "v"(hi));
    return r;
}
__device__ __forceinline__ void permswap(uint& a, uint& b) {
    asm("v_permlane32_swap_b32 %0, %1" : "+v"(a), "+v"(b));
}
__device__ __forceinline__ bf16x8 pack4(uint w0, uint w1, uint w2, uint w3) {
    union { uint u[4]; bf16x8 v; } t;
    t.u[0] = w0; t.u[1] = w1; t.u[2] = w2; t.u[3] = w3;
    return t.v;
}

__global__ __launch_bounds__(512, 2) void attn_mfma(const float* __restrict__ xq,
                                                    const uint16_t* __restrict__ kvg,
                                                    float* __restrict__ ao)
{
    __shared__ char lds[2][32768];

    const int b = blockIdx.x;
    const int kvh = b & 7;              // consecutive blocks -> different kv-heads -> XCD i%8 gets kv-head i (L2 locality)
    const int r = b >> 3;
    const int h = kvh * 4 + (r & 3);
    const int q0 = (r >> 2) * 256;
    const int tid = threadIdx.x;
    const int w = tid >> 6;
    const int lane = tid & 63;
    const int ln31 = lane & 31;
    const int hi = lane >> 5;

    // ---- Q fragments (hi/lo) in registers; Q already rope'd and pre-scaled by 1/sqrt(128) ----
    const int q = q0 + w * 32 + ln31;
    const float* qrow = xq + (size_t)q * 4096 + h * 128;
    bf16x8 Qh[8], Ql[8];
    #pragma unroll
    for (int ks = 0; ks < 8; ++ks) {
        float f[8];
        *reinterpret_cast<float4*>(&f[0]) = *reinterpret_cast<const float4*>(qrow + ks * 16 + hi * 8);
        *reinterpret_cast<float4*>(&f[4]) = *reinterpret_cast<const float4*>(qrow + ks * 16 + hi * 8 + 4);
        #pragma unroll
        for (int e = 0; e < 8; ++e) {
            bf16_t hb = (bf16_t)f[e];
            Qh[ks][e] = hb;
            Ql[ks][e] = (bf16_t)(f[e] - (float)hb);
        }
    }

    const char* gkv = (const char*)kvg + (size_t)kvh * 64 * 32768;

    f32x16 oacc[4] = {{}, {}, {}, {}};
    float m = -3.0e38f, l = 0.f;

    // prologue stage tile 0
    {
        const char* g = gkv;
        #pragma unroll
        for (int i = 0; i < 4; ++i) {
            const int chunk = i * 8 + w;
            __builtin_amdgcn_global_load_lds(
                (const __attribute__((address_space(1))) void*)(g + chunk * 1024 + lane * 16),
                (__attribute__((address_space(3))) void*)(&lds[0][chunk * 1024]),
                16, 0, 0);
        }
    }

    for (int t = 0; t < 64; ++t) {
        __syncthreads();           // tile t staged (drains vmcnt), prior reads of next buf done
        if (t + 1 < 64) {
            const char* g = gkv + (size_t)(t + 1) * 32768;
            const int buf = (t + 1) & 1;
            #pragma unroll
            for (int i = 0; i < 4; ++i) {
                const int chunk = i * 8 + w;
                __builtin_amdgcn_global_load_lds(
                    (const __attribute__((address_space(1))) void*)(g + chunk * 1024 + lane * 16),
                    (__attribute__((address_space(3))) void*)(&lds[buf][chunk * 1024]),
                    16, 0, 0);
            }
        }
        const int cur = t & 1;
        const char* Kh = lds[cur];
        const char* Kl = lds[cur] + 8192;
        const char* Vh = lds[cur] + 16384;
        const char* Vl = lds[cur] + 24576;

        // ---- swapped QK^T: S^T[kv][q] ----
        f32x16 s = {};
        #pragma unroll
        for (int ks = 0; ks < 8; ++ks) {
            const int row = ln31;
            const int byt = row * 256 + ((ks * 32 + hi * 16) ^ ((row & 15) << 4));
            bf16x8 ah = *reinterpret_cast<const bf16x8*>(Kh + byt);
            bf16x8 al = *reinterpret_cast<const bf16x8*>(Kl + byt);
            s = __builtin_amdgcn_mfma_f32_32x32x16_bf16(ah, Qh[ks], s, 0, 0, 0);
            s = __builtin_amdgcn_mfma_f32_32x32x16_bf16(al, Qh[ks], s, 0, 0, 0);
            s = __builtin_amdgcn_mfma_f32_32x32x16_bf16(ah, Ql[ks], s, 0, 0, 0);
        }

        // ---- online softmax (lane-local rows: 16 kv here, 16 in partner lane^32; same q) ----
        float mx = s[0];
        #pragma unroll
        for (int jj = 1; jj < 16; ++jj) mx = fmaxf(mx, s[jj]);
        mx = fmaxf(mx, __shfl_xor(mx, 32));
        const float mnew = fmaxf(m, mx);
        const float corr = __expf(m - mnew);
        m = mnew;
        float psum = 0.f;
        #pragma unroll
        for (int jj = 0; jj < 16; ++jj) {
            float pv = __expf(s[jj] - m);
            s[jj] = pv;
            psum += pv;
        }
        psum += __shfl_xor(psum, 32);
        l = l * corr + psum;
        #pragma unroll
        for (int dt = 0; dt < 4; ++dt) oacc[dt] *= corr;

        // ---- P -> bf16 hi/lo B-fragments + PV ----
        #pragma unroll
        for (int ks = 0; ks < 2; ++ks) {
            const int b0 = ks * 8;
            uint wa = cvtpk(s[b0 + 0], s[b0 + 1]);
            uint wb = cvtpk(s[b0 + 2], s[b0 + 3]);
            uint wc = cvtpk(s[b0 + 4], s[b0 + 5]);
            uint wd = cvtpk(s[b0 + 6], s[b0 + 7]);
            // residuals vs the exact bf16 used in the hi pass
            float r0 = s[b0 + 0] - __uint_as_float(wa << 16);
            float r1 = s[b0 + 1] - __uint_as_float(wa & 0xffff0000u);
            float r2 = s[b0 + 2] - __uint_as_float(wb << 16);
            float r3 = s[b0 + 3] - __uint_as_float(wb & 0xffff0000u);
            float r4 = s[b0 + 4] - __uint_as_float(wc << 16);
            float r5 = s[b0 + 5] - __uint_as_float(wc & 0xffff0000u);
            float r6 = s[b0 + 6] - __uint_as_float(wd << 16);
            float r7 = s[b0 + 7] - __uint_as_float(wd & 0xffff0000u);
            uint la = cvtpk(r0, r1);
            uint lb = cvtpk(r2, r3);
            uint lc = cvtpk(r4, r5);
            uint ld = cvtpk(r6, r7);
            permswap(wa, wc); permswap(wb, wd);
            permswap(la, lc); permswap(lb, ld);
            bf16x8 Pf  = pack4(wa, wb, wc, wd);
            bf16x8 Plf = pack4(la, lb, lc, ld);
            #pragma unroll
            for (int dt = 0; dt < 4; ++dt) {
                const int row = dt * 32 + ln31;
                const int byt = row * 64 + ((ks * 32 + hi * 16) ^ ((row & 3) << 4));
                bf16x8 vh = *reinterpret_cast<const bf16x8*>(Vh + byt);
                bf16x8 vl = *reinterpret_cast<const bf16x8*>(Vl + byt);
                oacc[dt] = __builtin_amdgcn_mfma_f32_32x32x16_bf16(vh, Pf,  oacc[dt], 0, 0, 0);
                oacc[dt] = __builtin_amdgcn_mfma_f32_32x32x16_bf16(vh, Plf, oacc[dt], 0, 0, 0);
                oacc[dt] = __builtin_amdgcn_mfma_f32_32x32x16_bf16(vl, Pf,  oacc[dt], 0, 0, 0);
            }
        }
    }

    // ---- epilogue: O^T acc -> ao[q][h*128 + d] ----
    const float invl = 1.0f / l;
    float* aorow = ao + (size_t)q * 4096 + h * 128;
    #pragma unroll
    for (int dt = 0; dt < 4; ++dt)
        #pragma unroll
        for (int g4 = 0; g4 < 4; ++g4) {
            float4 v;
            v.x = oacc[dt][g4 * 4 + 0] * invl;
            v.y = oacc[dt][g4 * 4 + 1] * invl;
            v.z = oacc[dt][g4 * 4 + 2] * invl;
            v.w = oacc[dt][g4 * 4 + 3] * invl;
            *reinterpret_cast<float4*>(aorow + dt * 32 + 8 * g4 + 4 * hi) = v;
        }
}

extern "C" void kernel_launch(void* const* d_in, const int* in_sizes, int n_in,
                              void* d_out, int out_size, void* d_ws, size_t ws_size,
                              hipStream_t stream)
{
    const float* x  = (const float*)d_in[0];
    const float* wq = (const float*)d_in[1];
    const float* wk = (const float*)d_in[2];
    const float* wv = (const float*)d_in[3];
    const float* wo = (const float*)d_in[4];
    float* out = (float*)d_out;

    float* ws = (float*)d_ws;
    float*    xq  = ws;                                  // [0, 8388608)
    uint16_t* kvg = (uint16_t*)(ws + 8388608);           // float slots [8388608, 12582912)
    float*    xk  = ws + 12582912;                       // [12582912, 14680064)
    float*    xv  = ws + 14680064;                       // [14680064, 16777216)
    float*    ao  = ws + 12582912;                       // aliases xk/xv after conv_kv; [12582912, 21301248)

    dim3 blk(256);
    gemm_hilo<<<dim3(32, 16), blk, 0, stream>>>(x, wq, xq, 2048, 4096, 4096);
    gemm_hilo<<<dim3(8, 16),  blk, 0, stream>>>(x, wk, xk, 2048, 1024, 4096);
    gemm_hilo<<<dim3(8, 16),  blk, 0, stream>>>(x, wv, xv, 2048, 1024, 4096);
    rope_k<<<dim3(20480), blk, 0, stream>>>(xq, xk);
    conv_kv<<<dim3(64, 8), blk, 0, stream>>>(xk, xv, kvg);
    attn_mfma<<<dim3(256), dim3(512), 0, stream>>>(xq, kvg, ao);
    gemm_hilo<<<dim3(32, 16), blk, 0, stream>>>(ao, wo, out, 2048, 4096, 4096);
}

// Round 3
// 908.977 us; speedup vs baseline: 3.1508x; 1.2410x over previous
//
#include <hip/hip_runtime.h>
#include <hip/hip_bf16.h>

typedef __bf16 bf16_t;
typedef unsigned int uint;
typedef __attribute__((ext_vector_type(8))) __bf16 bf16x8;
typedef __attribute__((ext_vector_type(4))) __bf16 bf16x4;
typedef __attribute__((ext_vector_type(4))) float f32x4;
typedef __attribute__((ext_vector_type(16))) float f32x16;

#define LDS_STRIDE 40

// ---------------- split fp32 -> (hi, lo) bf16 arrays, row-major ----------------
__global__ __launch_bounds__(256) void split_hl(const float* __restrict__ src,
                                                uint16_t* __restrict__ hi,
                                                uint16_t* __restrict__ lo, int n8)
{
    const int i = blockIdx.x * 256 + threadIdx.x;
    if (i >= n8) return;
    const float4 v0 = *reinterpret_cast<const float4*>(src + (size_t)i * 8);
    const float4 v1 = *reinterpret_cast<const float4*>(src + (size_t)i * 8 + 4);
    float f[8] = {v0.x, v0.y, v0.z, v0.w, v1.x, v1.y, v1.z, v1.w};
    bf16x8 h, l;
    #pragma unroll
    for (int e = 0; e < 8; ++e) {
        bf16_t hb = (bf16_t)f[e];
        h[e] = hb;
        l[e] = (bf16_t)(f[e] - (float)hb);
    }
    *reinterpret_cast<bf16x8*>(hi + (size_t)i * 8) = h;
    *reinterpret_cast<bf16x8*>(lo + (size_t)i * 8) = l;
}

// ---------------- 128x128 tile GEMM on pre-split operands, 3-pass hi/lo ----------------
// A[M][K], B[N][K] row-major bf16-bits; C row-major fp32. Ah/Al at A[row0][0],
// Bh/Bl at B[col0][0], Cp at C[row0][col0].
__device__ __forceinline__ void tile_mm(const uint16_t* __restrict__ Ah,
                                        const uint16_t* __restrict__ Al,
                                        const uint16_t* __restrict__ Bh,
                                        const uint16_t* __restrict__ Bl,
                                        int K, float* __restrict__ Cp, int ldc)
{
    __shared__ bf16_t sAh[128 * LDS_STRIDE];
    __shared__ bf16_t sAl[128 * LDS_STRIDE];
    __shared__ bf16_t sBh[128 * LDS_STRIDE];
    __shared__ bf16_t sBl[128 * LDS_STRIDE];

    const int tid  = threadIdx.x;
    const int lane = tid & 63;
    const int wave = tid >> 6;
    const int wr   = (wave >> 1) * 64;
    const int wc   = (wave & 1) * 64;

    f32x4 acc[4][4] = {};

    const int srow = tid >> 1;          // 0..127
    const int scol = (tid & 1) * 16;    // 0 or 16
    const size_t abase = (size_t)srow * K + scol;
    const int lbase = srow * LDS_STRIDE + scol;

    for (int kt = 0; kt < K; kt += 32) {
        const bf16x8 a0 = *reinterpret_cast<const bf16x8*>(Ah + abase + kt);
        const bf16x8 a1 = *reinterpret_cast<const bf16x8*>(Ah + abase + kt + 8);
        const bf16x8 l0 = *reinterpret_cast<const bf16x8*>(Al + abase + kt);
        const bf16x8 l1 = *reinterpret_cast<const bf16x8*>(Al + abase + kt + 8);
        const bf16x8 b0 = *reinterpret_cast<const bf16x8*>(Bh + abase + kt);
        const bf16x8 b1 = *reinterpret_cast<const bf16x8*>(Bh + abase + kt + 8);
        const bf16x8 m0 = *reinterpret_cast<const bf16x8*>(Bl + abase + kt);
        const bf16x8 m1 = *reinterpret_cast<const bf16x8*>(Bl + abase + kt + 8);

        *reinterpret_cast<bf16x8*>(&sAh[lbase])     = a0;
        *reinterpret_cast<bf16x8*>(&sAh[lbase + 8]) = a1;
        *reinterpret_cast<bf16x8*>(&sAl[lbase])     = l0;
        *reinterpret_cast<bf16x8*>(&sAl[lbase + 8]) = l1;
        *reinterpret_cast<bf16x8*>(&sBh[lbase])     = b0;
        *reinterpret_cast<bf16x8*>(&sBh[lbase + 8]) = b1;
        *reinterpret_cast<bf16x8*>(&sBl[lbase])     = m0;
        *reinterpret_cast<bf16x8*>(&sBl[lbase + 8]) = m1;
        __syncthreads();

        const int fr = lane & 15;
        const int kc = (lane >> 4) * 8;
        bf16x8 fah[4], fal[4], fbh[4], fbl[4];
        #pragma unroll
        for (int i = 0; i < 4; ++i) {
            const int ar = wr + i * 16 + fr;
            fah[i] = *reinterpret_cast<const bf16x8*>(&sAh[ar * LDS_STRIDE + kc]);
            fal[i] = *reinterpret_cast<const bf16x8*>(&sAl[ar * LDS_STRIDE + kc]);
            const int br = wc + i * 16 + fr;
            fbh[i] = *reinterpret_cast<const bf16x8*>(&sBh[br * LDS_STRIDE + kc]);
            fbl[i] = *reinterpret_cast<const bf16x8*>(&sBl[br * LDS_STRIDE + kc]);
        }

        #pragma unroll
        for (int i = 0; i < 4; ++i)
            #pragma unroll
            for (int j = 0; j < 4; ++j) {
                acc[i][j] = __builtin_amdgcn_mfma_f32_16x16x32_bf16(fah[i], fbh[j], acc[i][j], 0, 0, 0);
                acc[i][j] = __builtin_amdgcn_mfma_f32_16x16x32_bf16(fal[i], fbh[j], acc[i][j], 0, 0, 0);
                acc[i][j] = __builtin_amdgcn_mfma_f32_16x16x32_bf16(fah[i], fbl[j], acc[i][j], 0, 0, 0);
            }
        __syncthreads();
    }

    const int crow = wr + (lane >> 4) * 4;
    const int ccol = wc + (lane & 15);
    #pragma unroll
    for (int i = 0; i < 4; ++i)
        #pragma unroll
        for (int j = 0; j < 4; ++j)
            #pragma unroll
            for (int rr = 0; rr < 4; ++rr)
                Cp[(size_t)(crow + i * 16 + rr) * ldc + ccol + j * 16] = acc[i][j][rr];
}

// Merged QKV projection: grid (48, 16). bx<32 -> wq, <40 -> wk, else wv.
__global__ __launch_bounds__(256) void gemm_qkv(const uint16_t* __restrict__ xh,  const uint16_t* __restrict__ xl,
                                                const uint16_t* __restrict__ wqh, const uint16_t* __restrict__ wql,
                                                const uint16_t* __restrict__ wkh, const uint16_t* __restrict__ wkl,
                                                const uint16_t* __restrict__ wvh, const uint16_t* __restrict__ wvl,
                                                float* __restrict__ xq, float* __restrict__ xk, float* __restrict__ xv)
{
    const int bx = blockIdx.x, by = blockIdx.y;
    const uint16_t *Bh, *Bl;
    float* op;
    int ldc, cb;
    if (bx < 32)      { Bh = wqh; Bl = wql; op = xq; ldc = 4096; cb = bx; }
    else if (bx < 40) { Bh = wkh; Bl = wkl; op = xk; ldc = 1024; cb = bx - 32; }
    else              { Bh = wvh; Bl = wvl; op = xv; ldc = 1024; cb = bx - 40; }
    tile_mm(xh + (size_t)by * 128 * 4096, xl + (size_t)by * 128 * 4096,
            Bh + (size_t)cb * 128 * 4096, Bl + (size_t)cb * 128 * 4096,
            4096, op + (size_t)by * 128 * ldc + cb * 128, ldc);
}

__global__ __launch_bounds__(256) void gemm_out(const uint16_t* __restrict__ ah, const uint16_t* __restrict__ al,
                                                const uint16_t* __restrict__ bh, const uint16_t* __restrict__ bl,
                                                float* __restrict__ C)
{
    tile_mm(ah + (size_t)blockIdx.y * 128 * 4096, al + (size_t)blockIdx.y * 128 * 4096,
            bh + (size_t)blockIdx.x * 128 * 4096, bl + (size_t)blockIdx.x * 128 * 4096,
            4096, C + (size_t)blockIdx.y * 128 * 4096 + blockIdx.x * 128, 4096);
}

// ---------------- legacy fused-convert GEMM (fallback path if ws too small) ----------------
__global__ __launch_bounds__(256) void gemm_hilo(const float* __restrict__ A,
                                                 const float* __restrict__ B,
                                                 float* __restrict__ C,
                                                 int M, int N, int K)
{
    __shared__ bf16_t sAh[128 * LDS_STRIDE];
    __shared__ bf16_t sAl[128 * LDS_STRIDE];
    __shared__ bf16_t sBh[128 * LDS_STRIDE];
    __shared__ bf16_t sBl[128 * LDS_STRIDE];

    const int tid  = threadIdx.x;
    const int lane = tid & 63;
    const int wave = tid >> 6;
    const int wr   = (wave >> 1) * 64;
    const int wc   = (wave & 1) * 64;
    const int row0 = blockIdx.y * 128;
    const int col0 = blockIdx.x * 128;

    f32x4 acc[4][4] = {};

    const int lrow = tid >> 3;
    const int lcol = (tid & 7) * 4;

    for (int kt = 0; kt < K; kt += 32) {
        #pragma unroll
        for (int p = 0; p < 4; ++p) {
            const int row = p * 32 + lrow;
            const float4 va = *reinterpret_cast<const float4*>(&A[(size_t)(row0 + row) * K + kt + lcol]);
            const float4 vb = *reinterpret_cast<const float4*>(&B[(size_t)(col0 + row) * K + kt + lcol]);
            float fa[4] = {va.x, va.y, va.z, va.w};
            float fb[4] = {vb.x, vb.y, vb.z, vb.w};
            bf16x4 ah, al, bh, bl;
            #pragma unroll
            for (int e = 0; e < 4; ++e) {
                bf16_t hv = (bf16_t)fa[e];
                ah[e] = hv;
                al[e] = (bf16_t)(fa[e] - (float)hv);
                bf16_t g = (bf16_t)fb[e];
                bh[e] = g;
                bl[e] = (bf16_t)(fb[e] - (float)g);
            }
            *reinterpret_cast<bf16x4*>(&sAh[row * LDS_STRIDE + lcol]) = ah;
            *reinterpret_cast<bf16x4*>(&sAl[row * LDS_STRIDE + lcol]) = al;
            *reinterpret_cast<bf16x4*>(&sBh[row * LDS_STRIDE + lcol]) = bh;
            *reinterpret_cast<bf16x4*>(&sBl[row * LDS_STRIDE + lcol]) = bl;
        }
        __syncthreads();

        const int fr = lane & 15;
        const int kc = (lane >> 4) * 8;
        bf16x8 fah[4], fal[4], fbh[4], fbl[4];
        #pragma unroll
        for (int i = 0; i < 4; ++i) {
            const int ar = wr + i * 16 + fr;
            fah[i] = *reinterpret_cast<const bf16x8*>(&sAh[ar * LDS_STRIDE + kc]);
            fal[i] = *reinterpret_cast<const bf16x8*>(&sAl[ar * LDS_STRIDE + kc]);
            const int br = wc + i * 16 + fr;
            fbh[i] = *reinterpret_cast<const bf16x8*>(&sBh[br * LDS_STRIDE + kc]);
            fbl[i] = *reinterpret_cast<const bf16x8*>(&sBl[br * LDS_STRIDE + kc]);
        }

        #pragma unroll
        for (int i = 0; i < 4; ++i)
            #pragma unroll
            for (int j = 0; j < 4; ++j) {
                acc[i][j] = __builtin_amdgcn_mfma_f32_16x16x32_bf16(fah[i], fbh[j], acc[i][j], 0, 0, 0);
                acc[i][j] = __builtin_amdgcn_mfma_f32_16x16x32_bf16(fal[i], fbh[j], acc[i][j], 0, 0, 0);
                acc[i][j] = __builtin_amdgcn_mfma_f32_16x16x32_bf16(fah[i], fbl[j], acc[i][j], 0, 0, 0);
            }
        __syncthreads();
    }

    const int crow = row0 + wr + (lane >> 4) * 4;
    const int ccol = col0 + wc + (lane & 15);
    #pragma unroll
    for (int i = 0; i < 4; ++i)
        #pragma unroll
        for (int j = 0; j < 4; ++j)
            #pragma unroll
            for (int rr = 0; rr < 4; ++rr)
                C[(size_t)(crow + i * 16 + rr) * N + ccol + j * 16] = acc[i][j][rr];
}

// ---------------- RoPE in place; Q additionally scaled by 1/sqrt(128) ----------------
__global__ __launch_bounds__(256) void rope_k(float* __restrict__ xq, float* __restrict__ xk)
{
    const int idx = blockIdx.x * 256 + threadIdx.x;
    const int TOTQ = 2048 * 32 * 64;
    int s, j;
    float* base;
    bool isq = idx < TOTQ;
    if (isq) {
        s = idx >> 11;
        const int rem = idx & 2047;
        j = rem & 63;
        base = xq + (size_t)s * 4096 + (rem >> 6) * 128 + 2 * j;
    } else {
        const int i2 = idx - TOTQ;
        s = i2 >> 9;
        const int rem = i2 & 511;
        j = rem & 63;
        base = xk + (size_t)s * 1024 + (rem >> 6) * 128 + 2 * j;
    }
    const float invf = exp2f(-(float)j * (13.287712379549449f / 64.0f));
    const float ang = (float)s * invf;
    float sn, cs;
    sincosf(ang, &sn, &cs);
    float2 v = *reinterpret_cast<float2*>(base);
    float2 r;
    r.x = v.x * cs - v.y * sn;
    r.y = v.x * sn + v.y * cs;
    if (isq) { r.x *= 0.08838834764831845f; r.y *= 0.08838834764831845f; }
    *reinterpret_cast<float2*>(base) = r;
}

// ---------------- Convert roped K and raw V to blocked+swizzled bf16 hi/lo tiles ----------------
__global__ __launch_bounds__(256) void conv_kv(const float* __restrict__ xk,
                                               const float* __restrict__ xv,
                                               uint16_t* __restrict__ kvg)
{
    __shared__ float V[32][129];
    const int t = blockIdx.x;
    const int h = blockIdx.y;
    const int tid = threadIdx.x;
    uint16_t* tile = kvg + ((size_t)(h * 64 + t)) * 16384;

    #pragma unroll
    for (int i = 0; i < 4; ++i) {
        int v = i * 256 + tid;
        int row = v >> 5, c4 = (v & 31) * 4;
        *reinterpret_cast<float4*>(&V[row][c4]) =
            *reinterpret_cast<const float4*>(&xv[(size_t)(t * 32 + row) * 1024 + h * 128 + c4]);
    }

    {
        const int r = tid >> 3;
        const int d0 = (tid & 7) * 16;
        float f[16];
        const float* kr = &xk[(size_t)(t * 32 + r) * 1024 + h * 128 + d0];
        *reinterpret_cast<float4*>(&f[0])  = *reinterpret_cast<const float4*>(kr);
        *reinterpret_cast<float4*>(&f[4])  = *reinterpret_cast<const float4*>(kr + 4);
        *reinterpret_cast<float4*>(&f[8])  = *reinterpret_cast<const float4*>(kr + 8);
        *reinterpret_cast<float4*>(&f[12]) = *reinterpret_cast<const float4*>(kr + 12);
        #pragma unroll
        for (int cc = 0; cc < 2; ++cc) {
            bf16x8 hv, lv;
            #pragma unroll
            for (int e = 0; e < 8; ++e) {
                float x = f[cc * 8 + e];
                bf16_t hb = (bf16_t)x;
                hv[e] = hb;
                lv[e] = (bf16_t)(x - (float)hb);
            }
            const int c = (d0 >> 3) + cc;
            const int pos = r * 128 + ((c ^ (r & 15)) << 3);
            *reinterpret_cast<bf16x8*>(&tile[pos]) = hv;
            *reinterpret_cast<bf16x8*>(&tile[4096 + pos]) = lv;
        }
    }
    __syncthreads();
    {
        const int d = tid >> 1;
        const int k0 = (tid & 1) * 16;
        float g[16];
        #pragma unroll
        for (int j = 0; j < 16; ++j) g[j] = V[k0 + j][d];
        #pragma unroll
        for (int cc = 0; cc < 2; ++cc) {
            bf16x8 hv, lv;
            #pragma unroll
            for (int e = 0; e < 8; ++e) {
                float x = g[cc * 8 + e];
                bf16_t hb = (bf16_t)x;
                hv[e] = hb;
                lv[e] = (bf16_t)(x - (float)hb);
            }
            const int c = (k0 >> 3) + cc;
            const int pos = d * 32 + ((c ^ (d & 3)) << 3);
            *reinterpret_cast<bf16x8*>(&tile[8192 + pos]) = hv;
            *reinterpret_cast<bf16x8*>(&tile[12288 + pos]) = lv;
        }
    }
}

// ---------------- MFMA flash attention ----------------
__device__ __forceinline__ uint cvtpk(float lo, float hi) {
    uint r;
    asm("v_cvt_pk_bf16_f32 %0, %1, %2" : "=v"(r) : "v"(lo), "v"(hi));
    return r;
}
__device__ __forceinline__ void permswap(uint& a, uint& b) {
    asm("v_permlane32_swap_b32 %0, %1" : "+v"(a), "+v"(b));
}
__device__ __forceinline__ bf16x8 pack4(uint w0, uint w1, uint w2, uint w3) {
    union { uint u[4]; bf16x8 v; } t;
    t.u[0] = w0; t.u[1] = w1; t.u[2] = w2; t.u[3] = w3;
    return t.v;
}

__global__ __launch_bounds__(512, 2) void attn_mfma(const float* __restrict__ xq,
                                                    const uint16_t* __restrict__ kvg,
                                                    float* __restrict__ ao)
{
    __shared__ char lds[2][32768];

    const int b = blockIdx.x;
    const int kvh = b & 7;
    const int r = b >> 3;
    const int h = kvh * 4 + (r & 3);
    const int q0 = (r >> 2) * 256;
    const int tid = threadIdx.x;
    const int w = tid >> 6;
    const int lane = tid & 63;
    const int ln31 = lane & 31;
    const int hi = lane >> 5;

    const int q = q0 + w * 32 + ln31;
    const float* qrow = xq + (size_t)q * 4096 + h * 128;
    bf16x8 Qh[8], Ql[8];
    #pragma unroll
    for (int ks = 0; ks < 8; ++ks) {
        float f[8];
        *reinterpret_cast<float4*>(&f[0]) = *reinterpret_cast<const float4*>(qrow + ks * 16 + hi * 8);
        *reinterpret_cast<float4*>(&f[4]) = *reinterpret_cast<const float4*>(qrow + ks * 16 + hi * 8 + 4);
        #pragma unroll
        for (int e = 0; e < 8; ++e) {
            bf16_t hb = (bf16_t)f[e];
            Qh[ks][e] = hb;
            Ql[ks][e] = (bf16_t)(f[e] - (float)hb);
        }
    }

    const char* gkv = (const char*)kvg + (size_t)kvh * 64 * 32768;

    f32x16 oacc[4] = {{}, {}, {}, {}};
    float m = -3.0e38f, l = 0.f;

    {
        const char* g = gkv;
        #pragma unroll
        for (int i = 0; i < 4; ++i) {
            const int chunk = i * 8 + w;
            __builtin_amdgcn_global_load_lds(
                (const __attribute__((address_space(1))) void*)(g + chunk * 1024 + lane * 16),
                (__attribute__((address_space(3))) void*)(&lds[0][chunk * 1024]),
                16, 0, 0);
        }
    }

    for (int t = 0; t < 64; ++t) {
        __syncthreads();
        if (t + 1 < 64) {
            const char* g = gkv + (size_t)(t + 1) * 32768;
            const int buf = (t + 1) & 1;
            #pragma unroll
            for (int i = 0; i < 4; ++i) {
                const int chunk = i * 8 + w;
                __builtin_amdgcn_global_load_lds(
                    (const __attribute__((address_space(1))) void*)(g + chunk * 1024 + lane * 16),
                    (__attribute__((address_space(3))) void*)(&lds[buf][chunk * 1024]),
                    16, 0, 0);
            }
        }
        const int cur = t & 1;
        const char* Kh = lds[cur];
        const char* Kl = lds[cur] + 8192;
        const char* Vh = lds[cur] + 16384;
        const char* Vl = lds[cur] + 24576;

        f32x16 s = {};
        #pragma unroll
        for (int ks = 0; ks < 8; ++ks) {
            const int row = ln31;
            const int byt = row * 256 + ((ks * 32 + hi * 16) ^ ((row & 15) << 4));
            bf16x8 ah = *reinterpret_cast<const bf16x8*>(Kh + byt);
            bf16x8 al = *reinterpret_cast<const bf16x8*>(Kl + byt);
            s = __builtin_amdgcn_mfma_f32_32x32x16_bf16(ah, Qh[ks], s, 0, 0, 0);
            s = __builtin_amdgcn_mfma_f32_32x32x16_bf16(al, Qh[ks], s, 0, 0, 0);
            s = __builtin_amdgcn_mfma_f32_32x32x16_bf16(ah, Ql[ks], s, 0, 0, 0);
        }

        float mx = s[0];
        #pragma unroll
        for (int jj = 1; jj < 16; ++jj) mx = fmaxf(mx, s[jj]);
        mx = fmaxf(mx, __shfl_xor(mx, 32));
        const float mnew = fmaxf(m, mx);
        const float corr = __expf(m - mnew);
        m = mnew;
        float psum = 0.f;
        #pragma unroll
        for (int jj = 0; jj < 16; ++jj) {
            float pv = __expf(s[jj] - m);
            s[jj] = pv;
            psum += pv;
        }
        psum += __shfl_xor(psum, 32);
        l = l * corr + psum;
        #pragma unroll
        for (int dt = 0; dt < 4; ++dt) oacc[dt] *= corr;

        #pragma unroll
        for (int ks = 0; ks < 2; ++ks) {
            const int b0 = ks * 8;
            uint wa = cvtpk(s[b0 + 0], s[b0 + 1]);
            uint wb = cvtpk(s[b0 + 2], s[b0 + 3]);
            uint wc = cvtpk(s[b0 + 4], s[b0 + 5]);
            uint wd = cvtpk(s[b0 + 6], s[b0 + 7]);
            float r0 = s[b0 + 0] - __uint_as_float(wa << 16);
            float r1 = s[b0 + 1] - __uint_as_float(wa & 0xffff0000u);
            float r2 = s[b0 + 2] - __uint_as_float(wb << 16);
            float r3 = s[b0 + 3] - __uint_as_float(wb & 0xffff0000u);
            float r4 = s[b0 + 4] - __uint_as_float(wc << 16);
            float r5 = s[b0 + 5] - __uint_as_float(wc & 0xffff0000u);
            float r6 = s[b0 + 6] - __uint_as_float(wd << 16);
            float r7 = s[b0 + 7] - __uint_as_float(wd & 0xffff0000u);
            uint la = cvtpk(r0, r1);
            uint lb = cvtpk(r2, r3);
            uint lc = cvtpk(r4, r5);
            uint ld = cvtpk(r6, r7);
            permswap(wa, wc); permswap(wb, wd);
            permswap(la, lc); permswap(lb, ld);
            bf16x8 Pf  = pack4(wa, wb, wc, wd);
            bf16x8 Plf = pack4(la, lb, lc, ld);
            #pragma unroll
            for (int dt = 0; dt < 4; ++dt) {
                const int row = dt * 32 + ln31;
                const int byt = row * 64 + ((ks * 32 + hi * 16) ^ ((row & 3) << 4));
                bf16x8 vh = *reinterpret_cast<const bf16x8*>(Vh + byt);
                bf16x8 vl = *reinterpret_cast<const bf16x8*>(Vl + byt);
                oacc[dt] = __builtin_amdgcn_mfma_f32_32x32x16_bf16(vh, Pf,  oacc[dt], 0, 0, 0);
                oacc[dt] = __builtin_amdgcn_mfma_f32_32x32x16_bf16(vh, Plf, oacc[dt], 0, 0, 0);
                oacc[dt] = __builtin_amdgcn_mfma_f32_32x32x16_bf16(vl, Pf,  oacc[dt], 0, 0, 0);
            }
        }
    }

    const float invl = 1.0f / l;
    float* aorow = ao + (size_t)q * 4096 + h * 128;
    #pragma unroll
    for (int dt = 0; dt < 4; ++dt)
        #pragma unroll
        for (int g4 = 0; g4 < 4; ++g4) {
            float4 v;
            v.x = oacc[dt][g4 * 4 + 0] * invl;
            v.y = oacc[dt][g4 * 4 + 1] * invl;
            v.z = oacc[dt][g4 * 4 + 2] * invl;
            v.w = oacc[dt][g4 * 4 + 3] * invl;
            *reinterpret_cast<float4*>(aorow + dt * 32 + 8 * g4 + 4 * hi) = v;
        }
}

extern "C" void kernel_launch(void* const* d_in, const int* in_sizes, int n_in,
                              void* d_out, int out_size, void* d_ws, size_t ws_size,
                              hipStream_t stream)
{
    const float* x  = (const float*)d_in[0];
    const float* wq = (const float*)d_in[1];
    const float* wk = (const float*)d_in[2];
    const float* wv = (const float*)d_in[3];
    const float* wo = (const float*)d_in[4];
    float* out = (float*)d_out;

    float* ws = (float*)d_ws;
    // Common layout (float-slot offsets)
    float*    xq  = ws;                          // [0, 8388608)
    uint16_t* kvg = (uint16_t*)(ws + 8388608);   // [8388608, 12582912)
    float*    xk  = ws + 12582912;               // [12582912, 14680064)
    float*    xv  = ws + 14680064;               // [14680064, 16777216)
    float*    ao  = ws + 12582912;               // aliases xk/xv after conv_kv

    dim3 blk(256);
    const size_t NEED = (size_t)54525952 * 4;

    if (ws_size >= NEED) {
        // pre-split path
        uint16_t* xh  = (uint16_t*)(ws + 20971520);   // 8.4M elems
        uint16_t* xl  = (uint16_t*)(ws + 25165824);
        uint16_t* wqh = (uint16_t*)(ws + 29360128);   // 16.8M elems
        uint16_t* wql = (uint16_t*)(ws + 37748736);
        uint16_t* wkh = (uint16_t*)(ws + 46137344);   // 4.2M elems
        uint16_t* wkl = (uint16_t*)(ws + 48234496);
        uint16_t* wvh = (uint16_t*)(ws + 50331648);
        uint16_t* wvl = (uint16_t*)(ws + 52428800);
        uint16_t* aoh = (uint16_t*)(ws);              // alias xq after attn
        uint16_t* aol = (uint16_t*)(ws + 4194304);
        uint16_t* woh = wqh;                           // alias wq split after QKV
        uint16_t* wol = wql;

        split_hl<<<dim3(4096), blk, 0, stream>>>(x,  xh,  xl,  1048576);
        split_hl<<<dim3(8192), blk, 0, stream>>>(wq, wqh, wql, 2097152);
        split_hl<<<dim3(2048), blk, 0, stream>>>(wk, wkh, wkl, 524288);
        split_hl<<<dim3(2048), blk, 0, stream>>>(wv, wvh, wvl, 524288);
        gemm_qkv<<<dim3(48, 16), blk, 0, stream>>>(xh, xl, wqh, wql, wkh, wkl, wvh, wvl, xq, xk, xv);
        split_hl<<<dim3(8192), blk, 0, stream>>>(wo, woh, wol, 2097152);
        rope_k<<<dim3(20480), blk, 0, stream>>>(xq, xk);
        conv_kv<<<dim3(64, 8), blk, 0, stream>>>(xk, xv, kvg);
        attn_mfma<<<dim3(256), dim3(512), 0, stream>>>(xq, kvg, ao);
        split_hl<<<dim3(4096), blk, 0, stream>>>(ao, aoh, aol, 1048576);
        gemm_out<<<dim3(32, 16), blk, 0, stream>>>(aoh, aol, woh, wol, out);
    } else {
        // round-2 fallback
        gemm_hilo<<<dim3(32, 16), blk, 0, stream>>>(x, wq, xq, 2048, 4096, 4096);
        gemm_hilo<<<dim3(8, 16),  blk, 0, stream>>>(x, wk, xk, 2048, 1024, 4096);
        gemm_hilo<<<dim3(8, 16),  blk, 0, stream>>>(x, wv, xv, 2048, 1024, 4096);
        rope_k<<<dim3(20480), blk, 0, stream>>>(xq, xk);
        conv_kv<<<dim3(64, 8), blk, 0, stream>>>(xk, xv, kvg);
        attn_mfma<<<dim3(256), dim3(512), 0, stream>>>(xq, kvg, ao);
        gemm_hilo<<<dim3(32, 16), blk, 0, stream>>>(ao, wo, out, 2048, 4096, 4096);
    }
}

// Round 4
// 877.074 us; speedup vs baseline: 3.2654x; 1.0364x over previous
//
#include <hip/hip_runtime.h>
#include <hip/hip_bf16.h>

typedef __bf16 bf16_t;
typedef unsigned int uint;
typedef __attribute__((ext_vector_type(8))) __bf16 bf16x8;
typedef __attribute__((ext_vector_type(4))) __bf16 bf16x4;
typedef __attribute__((ext_vector_type(4))) float f32x4;
typedef __attribute__((ext_vector_type(16))) float f32x16;

#define LDS_STRIDE 40

// ---------------- split fp32 -> (hi, lo) bf16 arrays, row-major ----------------
__global__ __launch_bounds__(256) void split_hl(const float* __restrict__ src,
                                                uint16_t* __restrict__ hi,
                                                uint16_t* __restrict__ lo, int n8)
{
    const int i = blockIdx.x * 256 + threadIdx.x;
    if (i >= n8) return;
    const float4 v0 = *reinterpret_cast<const float4*>(src + (size_t)i * 8);
    const float4 v1 = *reinterpret_cast<const float4*>(src + (size_t)i * 8 + 4);
    float f[8] = {v0.x, v0.y, v0.z, v0.w, v1.x, v1.y, v1.z, v1.w};
    bf16x8 h, l;
    #pragma unroll
    for (int e = 0; e < 8; ++e) {
        bf16_t hb = (bf16_t)f[e];
        h[e] = hb;
        l[e] = (bf16_t)(f[e] - (float)hb);
    }
    *reinterpret_cast<bf16x8*>(hi + (size_t)i * 8) = h;
    *reinterpret_cast<bf16x8*>(lo + (size_t)i * 8) = l;
}

// ---------------- 128x128 tile GEMM, double-buffered global_load_lds staging ----------------
// Operands: row-major hi/lo bf16-bit arrays (pre-offset to tile corner). Per K-step (BK=32):
// LDS = 4 arrays x [128][32] linear, bank-swizzled via gather (slot ^= (row>>1)&3).
// 2-phase pipeline: stage tile t+1 into buf^1 before computing tile t; one barrier/K-step.
__device__ __forceinline__ void tile_mm2(const uint16_t* __restrict__ Ah,
                                         const uint16_t* __restrict__ Al,
                                         const uint16_t* __restrict__ Bh,
                                         const uint16_t* __restrict__ Bl,
                                         int K, float* __restrict__ Cp, int ldc)
{
    __shared__ char lds[2][32768];

    const int tid  = threadIdx.x;
    const int lane = tid & 63;
    const int w    = tid >> 6;
    const int wr   = (w >> 1) * 64;
    const int wc   = (w & 1) * 64;

    f32x4 acc[4][4] = {};

    // per-thread gather sources: unit u = (i*4+w)*64 + lane -> (row r, stored slot u&3)
    // original slot = (u&3) ^ ((r>>1)&3); src = arr + r*K + slot*8 (+kt)
    const uint16_t* sp[8];
    int dof[8];
    {
        const uint16_t* srcs[4] = {Ah, Al, Bh, Bl};
        #pragma unroll
        for (int a = 0; a < 4; ++a)
            #pragma unroll
            for (int i = 0; i < 2; ++i) {
                const int chunk = i * 4 + w;
                const int u = chunk * 64 + lane;
                const int r = u >> 2;
                const int s = (u & 3) ^ ((r >> 1) & 3);
                sp[a * 2 + i]  = srcs[a] + (size_t)r * K + s * 8;
                dof[a * 2 + i] = a * 8192 + chunk * 1024;
            }
    }

    // prologue: stage tile 0
    #pragma unroll
    for (int j = 0; j < 8; ++j)
        __builtin_amdgcn_global_load_lds(
            (const __attribute__((address_space(1))) void*)(sp[j]),
            (__attribute__((address_space(3))) void*)(&lds[0][0] + dof[j]),
            16, 0, 0);
    __syncthreads();

    const int NT = K >> 5;
    const int fr = lane & 15;
    const int s4 = lane >> 4;          // k-slot 0..3 (8 elems each)

    for (int t = 0; t < NT; ++t) {
        if (t + 1 < NT) {
            const int kt = (t + 1) * 32;
            char* nb = &lds[(t + 1) & 1][0];
            #pragma unroll
            for (int j = 0; j < 8; ++j)
                __builtin_amdgcn_global_load_lds(
                    (const __attribute__((address_space(1))) void*)(sp[j] + kt),
                    (__attribute__((address_space(3))) void*)(nb + dof[j]),
                    16, 0, 0);
        }
        const char* b = &lds[t & 1][0];

        bf16x8 fah[4], fal[4], fbh[4], fbl[4];
        #pragma unroll
        for (int i = 0; i < 4; ++i) {
            const int ar = wr + i * 16 + fr;
            const int aoff = ar * 64 + ((s4 ^ ((ar >> 1) & 3)) << 4);
            fah[i] = *reinterpret_cast<const bf16x8*>(b + aoff);
            fal[i] = *reinterpret_cast<const bf16x8*>(b + 8192 + aoff);
            const int br = wc + i * 16 + fr;
            const int boff = br * 64 + ((s4 ^ ((br >> 1) & 3)) << 4);
            fbh[i] = *reinterpret_cast<const bf16x8*>(b + 16384 + boff);
            fbl[i] = *reinterpret_cast<const bf16x8*>(b + 24576 + boff);
        }

        #pragma unroll
        for (int i = 0; i < 4; ++i)
            #pragma unroll
            for (int j = 0; j < 4; ++j) {
                acc[i][j] = __builtin_amdgcn_mfma_f32_16x16x32_bf16(fah[i], fbh[j], acc[i][j], 0, 0, 0);
                acc[i][j] = __builtin_amdgcn_mfma_f32_16x16x32_bf16(fal[i], fbh[j], acc[i][j], 0, 0, 0);
                acc[i][j] = __builtin_amdgcn_mfma_f32_16x16x32_bf16(fah[i], fbl[j], acc[i][j], 0, 0, 0);
            }
        __syncthreads();   // drains vmcnt(0)+lgkmcnt(0): next tile staged, all reads of buf done
    }

    const int crow = wr + ((lane >> 4) << 2);
    const int ccol = wc + (lane & 15);
    #pragma unroll
    for (int i = 0; i < 4; ++i)
        #pragma unroll
        for (int j = 0; j < 4; ++j)
            #pragma unroll
            for (int rr = 0; rr < 4; ++rr)
                Cp[(size_t)(crow + i * 16 + rr) * ldc + ccol + j * 16] = acc[i][j][rr];
}

// Merged QKV projection. grid 768 (1D), XCD-chunked bijective swizzle (768%8==0).
__global__ __launch_bounds__(256) void gemm_qkv2(const uint16_t* __restrict__ xh,  const uint16_t* __restrict__ xl,
                                                 const uint16_t* __restrict__ wqh, const uint16_t* __restrict__ wql,
                                                 const uint16_t* __restrict__ wkh, const uint16_t* __restrict__ wkl,
                                                 const uint16_t* __restrict__ wvh, const uint16_t* __restrict__ wvl,
                                                 float* __restrict__ xq, float* __restrict__ xk, float* __restrict__ xv)
{
    const int bid = blockIdx.x;
    const int swz = (bid & 7) * 96 + (bid >> 3);  // each XCD: 96 consecutive swz = 2 A-panels
    const int by = swz / 48;
    const int bx = swz % 48;
    const uint16_t *Bh, *Bl;
    float* op;
    int ldc, cb;
    if (bx < 32)      { Bh = wqh; Bl = wql; op = xq; ldc = 4096; cb = bx; }
    else if (bx < 40) { Bh = wkh; Bl = wkl; op = xk; ldc = 1024; cb = bx - 32; }
    else              { Bh = wvh; Bl = wvl; op = xv; ldc = 1024; cb = bx - 40; }
    tile_mm2(xh + (size_t)by * 128 * 4096, xl + (size_t)by * 128 * 4096,
             Bh + (size_t)cb * 128 * 4096, Bl + (size_t)cb * 128 * 4096,
             4096, op + (size_t)by * 128 * ldc + cb * 128, ldc);
}

// Output projection. grid 512 (1D), XCD swizzle (512%8==0).
__global__ __launch_bounds__(256) void gemm_out2(const uint16_t* __restrict__ ah, const uint16_t* __restrict__ al,
                                                 const uint16_t* __restrict__ bh, const uint16_t* __restrict__ bl,
                                                 float* __restrict__ C)
{
    const int bid = blockIdx.x;
    const int swz = (bid & 7) * 64 + (bid >> 3);
    const int by = swz >> 5;
    const int bx = swz & 31;
    tile_mm2(ah + (size_t)by * 128 * 4096, al + (size_t)by * 128 * 4096,
             bh + (size_t)bx * 128 * 4096, bl + (size_t)bx * 128 * 4096,
             4096, C + (size_t)by * 128 * 4096 + bx * 128, 4096);
}

// ---------------- legacy fused-convert GEMM (fallback path if ws too small) ----------------
__global__ __launch_bounds__(256) void gemm_hilo(const float* __restrict__ A,
                                                 const float* __restrict__ B,
                                                 float* __restrict__ C,
                                                 int M, int N, int K)
{
    __shared__ bf16_t sAh[128 * LDS_STRIDE];
    __shared__ bf16_t sAl[128 * LDS_STRIDE];
    __shared__ bf16_t sBh[128 * LDS_STRIDE];
    __shared__ bf16_t sBl[128 * LDS_STRIDE];

    const int tid  = threadIdx.x;
    const int lane = tid & 63;
    const int wave = tid >> 6;
    const int wr   = (wave >> 1) * 64;
    const int wc   = (wave & 1) * 64;
    const int row0 = blockIdx.y * 128;
    const int col0 = blockIdx.x * 128;

    f32x4 acc[4][4] = {};

    const int lrow = tid >> 3;
    const int lcol = (tid & 7) * 4;

    for (int kt = 0; kt < K; kt += 32) {
        #pragma unroll
        for (int p = 0; p < 4; ++p) {
            const int row = p * 32 + lrow;
            const float4 va = *reinterpret_cast<const float4*>(&A[(size_t)(row0 + row) * K + kt + lcol]);
            const float4 vb = *reinterpret_cast<const float4*>(&B[(size_t)(col0 + row) * K + kt + lcol]);
            float fa[4] = {va.x, va.y, va.z, va.w};
            float fb[4] = {vb.x, vb.y, vb.z, vb.w};
            bf16x4 ah, al, bh, bl;
            #pragma unroll
            for (int e = 0; e < 4; ++e) {
                bf16_t hv = (bf16_t)fa[e];
                ah[e] = hv;
                al[e] = (bf16_t)(fa[e] - (float)hv);
                bf16_t g = (bf16_t)fb[e];
                bh[e] = g;
                bl[e] = (bf16_t)(fb[e] - (float)g);
            }
            *reinterpret_cast<bf16x4*>(&sAh[row * LDS_STRIDE + lcol]) = ah;
            *reinterpret_cast<bf16x4*>(&sAl[row * LDS_STRIDE + lcol]) = al;
            *reinterpret_cast<bf16x4*>(&sBh[row * LDS_STRIDE + lcol]) = bh;
            *reinterpret_cast<bf16x4*>(&sBl[row * LDS_STRIDE + lcol]) = bl;
        }
        __syncthreads();

        const int fr = lane & 15;
        const int kc = (lane >> 4) * 8;
        bf16x8 fah[4], fal[4], fbh[4], fbl[4];
        #pragma unroll
        for (int i = 0; i < 4; ++i) {
            const int ar = wr + i * 16 + fr;
            fah[i] = *reinterpret_cast<const bf16x8*>(&sAh[ar * LDS_STRIDE + kc]);
            fal[i] = *reinterpret_cast<const bf16x8*>(&sAl[ar * LDS_STRIDE + kc]);
            const int br = wc + i * 16 + fr;
            fbh[i] = *reinterpret_cast<const bf16x8*>(&sBh[br * LDS_STRIDE + kc]);
            fbl[i] = *reinterpret_cast<const bf16x8*>(&sBl[br * LDS_STRIDE + kc]);
        }

        #pragma unroll
        for (int i = 0; i < 4; ++i)
            #pragma unroll
            for (int j = 0; j < 4; ++j) {
                acc[i][j] = __builtin_amdgcn_mfma_f32_16x16x32_bf16(fah[i], fbh[j], acc[i][j], 0, 0, 0);
                acc[i][j] = __builtin_amdgcn_mfma_f32_16x16x32_bf16(fal[i], fbh[j], acc[i][j], 0, 0, 0);
                acc[i][j] = __builtin_amdgcn_mfma_f32_16x16x32_bf16(fah[i], fbl[j], acc[i][j], 0, 0, 0);
            }
        __syncthreads();
    }

    const int crow = row0 + wr + (lane >> 4) * 4;
    const int ccol = col0 + wc + (lane & 15);
    #pragma unroll
    for (int i = 0; i < 4; ++i)
        #pragma unroll
        for (int j = 0; j < 4; ++j)
            #pragma unroll
            for (int rr = 0; rr < 4; ++rr)
                C[(size_t)(crow + i * 16 + rr) * N + ccol + j * 16] = acc[i][j][rr];
}

// ---------------- RoPE in place; Q additionally scaled by 1/sqrt(128) ----------------
__global__ __launch_bounds__(256) void rope_k(float* __restrict__ xq, float* __restrict__ xk)
{
    const int idx = blockIdx.x * 256 + threadIdx.x;
    const int TOTQ = 2048 * 32 * 64;
    int s, j;
    float* base;
    bool isq = idx < TOTQ;
    if (isq) {
        s = idx >> 11;
        const int rem = idx & 2047;
        j = rem & 63;
        base = xq + (size_t)s * 4096 + (rem >> 6) * 128 + 2 * j;
    } else {
        const int i2 = idx - TOTQ;
        s = i2 >> 9;
        const int rem = i2 & 511;
        j = rem & 63;
        base = xk + (size_t)s * 1024 + (rem >> 6) * 128 + 2 * j;
    }
    const float invf = exp2f(-(float)j * (13.287712379549449f / 64.0f));
    const float ang = (float)s * invf;
    float sn, cs;
    sincosf(ang, &sn, &cs);
    float2 v = *reinterpret_cast<float2*>(base);
    float2 r;
    r.x = v.x * cs - v.y * sn;
    r.y = v.x * sn + v.y * cs;
    if (isq) { r.x *= 0.08838834764831845f; r.y *= 0.08838834764831845f; }
    *reinterpret_cast<float2*>(base) = r;
}

// ---------------- Convert roped K and raw V to blocked+swizzled bf16 hi/lo tiles ----------------
__global__ __launch_bounds__(256) void conv_kv(const float* __restrict__ xk,
                                               const float* __restrict__ xv,
                                               uint16_t* __restrict__ kvg)
{
    __shared__ float V[32][129];
    const int t = blockIdx.x;
    const int h = blockIdx.y;
    const int tid = threadIdx.x;
    uint16_t* tile = kvg + ((size_t)(h * 64 + t)) * 16384;

    #pragma unroll
    for (int i = 0; i < 4; ++i) {
        int v = i * 256 + tid;
        int row = v >> 5, c4 = (v & 31) * 4;
        *reinterpret_cast<float4*>(&V[row][c4]) =
            *reinterpret_cast<const float4*>(&xv[(size_t)(t * 32 + row) * 1024 + h * 128 + c4]);
    }

    {
        const int r = tid >> 3;
        const int d0 = (tid & 7) * 16;
        float f[16];
        const float* kr = &xk[(size_t)(t * 32 + r) * 1024 + h * 128 + d0];
        *reinterpret_cast<float4*>(&f[0])  = *reinterpret_cast<const float4*>(kr);
        *reinterpret_cast<float4*>(&f[4])  = *reinterpret_cast<const float4*>(kr + 4);
        *reinterpret_cast<float4*>(&f[8])  = *reinterpret_cast<const float4*>(kr + 8);
        *reinterpret_cast<float4*>(&f[12]) = *reinterpret_cast<const float4*>(kr + 12);
        #pragma unroll
        for (int cc = 0; cc < 2; ++cc) {
            bf16x8 hv, lv;
            #pragma unroll
            for (int e = 0; e < 8; ++e) {
                float x = f[cc * 8 + e];
                bf16_t hb = (bf16_t)x;
                hv[e] = hb;
                lv[e] = (bf16_t)(x - (float)hb);
            }
            const int c = (d0 >> 3) + cc;
            const int pos = r * 128 + ((c ^ (r & 15)) << 3);
            *reinterpret_cast<bf16x8*>(&tile[pos]) = hv;
            *reinterpret_cast<bf16x8*>(&tile[4096 + pos]) = lv;
        }
    }
    __syncthreads();
    {
        const int d = tid >> 1;
        const int k0 = (tid & 1) * 16;
        float g[16];
        #pragma unroll
        for (int j = 0; j < 16; ++j) g[j] = V[k0 + j][d];
        #pragma unroll
        for (int cc = 0; cc < 2; ++cc) {
            bf16x8 hv, lv;
            #pragma unroll
            for (int e = 0; e < 8; ++e) {
                float x = g[cc * 8 + e];
                bf16_t hb = (bf16_t)x;
                hv[e] = hb;
                lv[e] = (bf16_t)(x - (float)hb);
            }
            const int c = (k0 >> 3) + cc;
            const int pos = d * 32 + ((c ^ (d & 3)) << 3);
            *reinterpret_cast<bf16x8*>(&tile[8192 + pos]) = hv;
            *reinterpret_cast<bf16x8*>(&tile[12288 + pos]) = lv;
        }
    }
}

// ---------------- MFMA flash attention ----------------
__device__ __forceinline__ uint cvtpk(float lo, float hi) {
    uint r;
    asm("v_cvt_pk_bf16_f32 %0, %1, %2" : "=v"(r) : "v"(lo), "v"(hi));
    return r;
}
__device__ __forceinline__ void permswap(uint& a, uint& b) {
    asm("v_permlane32_swap_b32 %0, %1" : "+v"(a), "+v"(b));
}
__device__ __forceinline__ bf16x8 pack4(uint w0, uint w1, uint w2, uint w3) {
    union { uint u[4]; bf16x8 v; } t;
    t.u[0] = w0; t.u[1] = w1; t.u[2] = w2; t.u[3] = w3;
    return t.v;
}

__global__ __launch_bounds__(512, 2) void attn_mfma(const float* __restrict__ xq,
                                                    const uint16_t* __restrict__ kvg,
                                                    float* __restrict__ ao)
{
    __shared__ char lds[2][32768];

    const int b = blockIdx.x;
    const int kvh = b & 7;
    const int r = b >> 3;
    const int h = kvh * 4 + (r & 3);
    const int q0 = (r >> 2) * 256;
    const int tid = threadIdx.x;
    const int w = tid >> 6;
    const int lane = tid & 63;
    const int ln31 = lane & 31;
    const int hi = lane >> 5;

    const int q = q0 + w * 32 + ln31;
    const float* qrow = xq + (size_t)q * 4096 + h * 128;
    bf16x8 Qh[8], Ql[8];
    #pragma unroll
    for (int ks = 0; ks < 8; ++ks) {
        float f[8];
        *reinterpret_cast<float4*>(&f[0]) = *reinterpret_cast<const float4*>(qrow + ks * 16 + hi * 8);
        *reinterpret_cast<float4*>(&f[4]) = *reinterpret_cast<const float4*>(qrow + ks * 16 + hi * 8 + 4);
        #pragma unroll
        for (int e = 0; e < 8; ++e) {
            bf16_t hb = (bf16_t)f[e];
            Qh[ks][e] = hb;
            Ql[ks][e] = (bf16_t)(f[e] - (float)hb);
        }
    }

    const char* gkv = (const char*)kvg + (size_t)kvh * 64 * 32768;

    f32x16 oacc[4] = {{}, {}, {}, {}};
    float m = -3.0e38f, l = 0.f;

    {
        const char* g = gkv;
        #pragma unroll
        for (int i = 0; i < 4; ++i) {
            const int chunk = i * 8 + w;
            __builtin_amdgcn_global_load_lds(
                (const __attribute__((address_space(1))) void*)(g + chunk * 1024 + lane * 16),
                (__attribute__((address_space(3))) void*)(&lds[0][chunk * 1024]),
                16, 0, 0);
        }
    }

    for (int t = 0; t < 64; ++t) {
        __syncthreads();
        if (t + 1 < 64) {
            const char* g = gkv + (size_t)(t + 1) * 32768;
            const int buf = (t + 1) & 1;
            #pragma unroll
            for (int i = 0; i < 4; ++i) {
                const int chunk = i * 8 + w;
                __builtin_amdgcn_global_load_lds(
                    (const __attribute__((address_space(1))) void*)(g + chunk * 1024 + lane * 16),
                    (__attribute__((address_space(3))) void*)(&lds[buf][chunk * 1024]),
                    16, 0, 0);
            }
        }
        const int cur = t & 1;
        const char* Kh = lds[cur];
        const char* Kl = lds[cur] + 8192;
        const char* Vh = lds[cur] + 16384;
        const char* Vl = lds[cur] + 24576;

        f32x16 s = {};
        #pragma unroll
        for (int ks = 0; ks < 8; ++ks) {
            const int row = ln31;
            const int byt = row * 256 + ((ks * 32 + hi * 16) ^ ((row & 15) << 4));
            bf16x8 ah = *reinterpret_cast<const bf16x8*>(Kh + byt);
            bf16x8 al = *reinterpret_cast<const bf16x8*>(Kl + byt);
            s = __builtin_amdgcn_mfma_f32_32x32x16_bf16(ah, Qh[ks], s, 0, 0, 0);
            s = __builtin_amdgcn_mfma_f32_32x32x16_bf16(al, Qh[ks], s, 0, 0, 0);
            s = __builtin_amdgcn_mfma_f32_32x32x16_bf16(ah, Ql[ks], s, 0, 0, 0);
        }

        float mx = s[0];
        #pragma unroll
        for (int jj = 1; jj < 16; ++jj) mx = fmaxf(mx, s[jj]);
        mx = fmaxf(mx, __shfl_xor(mx, 32));
        const float mnew = fmaxf(m, mx);
        const float corr = __expf(m - mnew);
        m = mnew;
        float psum = 0.f;
        #pragma unroll
        for (int jj = 0; jj < 16; ++jj) {
            float pv = __expf(s[jj] - m);
            s[jj] = pv;
            psum += pv;
        }
        psum += __shfl_xor(psum, 32);
        l = l * corr + psum;
        #pragma unroll
        for (int dt = 0; dt < 4; ++dt) oacc[dt] *= corr;

        #pragma unroll
        for (int ks = 0; ks < 2; ++ks) {
            const int b0 = ks * 8;
            uint wa = cvtpk(s[b0 + 0], s[b0 + 1]);
            uint wb = cvtpk(s[b0 + 2], s[b0 + 3]);
            uint wc = cvtpk(s[b0 + 4], s[b0 + 5]);
            uint wd = cvtpk(s[b0 + 6], s[b0 + 7]);
            float r0 = s[b0 + 0] - __uint_as_float(wa << 16);
            float r1 = s[b0 + 1] - __uint_as_float(wa & 0xffff0000u);
            float r2 = s[b0 + 2] - __uint_as_float(wb << 16);
            float r3 = s[b0 + 3] - __uint_as_float(wb & 0xffff0000u);
            float r4 = s[b0 + 4] - __uint_as_float(wc << 16);
            float r5 = s[b0 + 5] - __uint_as_float(wc & 0xffff0000u);
            float r6 = s[b0 + 6] - __uint_as_float(wd << 16);
            float r7 = s[b0 + 7] - __uint_as_float(wd & 0xffff0000u);
            uint la = cvtpk(r0, r1);
            uint lb = cvtpk(r2, r3);
            uint lc = cvtpk(r4, r5);
            uint ld = cvtpk(r6, r7);
            permswap(wa, wc); permswap(wb, wd);
            permswap(la, lc); permswap(lb, ld);
            bf16x8 Pf  = pack4(wa, wb, wc, wd);
            bf16x8 Plf = pack4(la, lb, lc, ld);
            #pragma unroll
            for (int dt = 0; dt < 4; ++dt) {
                const int row = dt * 32 + ln31;
                const int byt = row * 64 + ((ks * 32 + hi * 16) ^ ((row & 3) << 4));
                bf16x8 vh = *reinterpret_cast<const bf16x8*>(Vh + byt);
                bf16x8 vl = *reinterpret_cast<const bf16x8*>(Vl + byt);
                oacc[dt] = __builtin_amdgcn_mfma_f32_32x32x16_bf16(vh, Pf,  oacc[dt], 0, 0, 0);
                oacc[dt] = __builtin_amdgcn_mfma_f32_32x32x16_bf16(vh, Plf, oacc[dt], 0, 0, 0);
                oacc[dt] = __builtin_amdgcn_mfma_f32_32x32x16_bf16(vl, Pf,  oacc[dt], 0, 0, 0);
            }
        }
    }

    const float invl = 1.0f / l;
    float* aorow = ao + (size_t)q * 4096 + h * 128;
    #pragma unroll
    for (int dt = 0; dt < 4; ++dt)
        #pragma unroll
        for (int g4 = 0; g4 < 4; ++g4) {
            float4 v;
            v.x = oacc[dt][g4 * 4 + 0] * invl;
            v.y = oacc[dt][g4 * 4 + 1] * invl;
            v.z = oacc[dt][g4 * 4 + 2] * invl;
            v.w = oacc[dt][g4 * 4 + 3] * invl;
            *reinterpret_cast<float4*>(aorow + dt * 32 + 8 * g4 + 4 * hi) = v;
        }
}

extern "C" void kernel_launch(void* const* d_in, const int* in_sizes, int n_in,
                              void* d_out, int out_size, void* d_ws, size_t ws_size,
                              hipStream_t stream)
{
    const float* x  = (const float*)d_in[0];
    const float* wq = (const float*)d_in[1];
    const float* wk = (const float*)d_in[2];
    const float* wv = (const float*)d_in[3];
    const float* wo = (const float*)d_in[4];
    float* out = (float*)d_out;

    float* ws = (float*)d_ws;
    float*    xq  = ws;                          // [0, 8388608)
    uint16_t* kvg = (uint16_t*)(ws + 8388608);   // [8388608, 12582912)
    float*    xk  = ws + 12582912;               // [12582912, 14680064)
    float*    xv  = ws + 14680064;               // [14680064, 16777216)
    float*    ao  = ws + 12582912;               // aliases xk/xv after conv_kv

    dim3 blk(256);
    const size_t NEED = (size_t)54525952 * 4;

    if (ws_size >= NEED) {
        uint16_t* xh  = (uint16_t*)(ws + 20971520);
        uint16_t* xl  = (uint16_t*)(ws + 25165824);
        uint16_t* wqh = (uint16_t*)(ws + 29360128);
        uint16_t* wql = (uint16_t*)(ws + 37748736);
        uint16_t* wkh = (uint16_t*)(ws + 46137344);
        uint16_t* wkl = (uint16_t*)(ws + 48234496);
        uint16_t* wvh = (uint16_t*)(ws + 50331648);
        uint16_t* wvl = (uint16_t*)(ws + 52428800);
        uint16_t* aoh = (uint16_t*)(ws);              // alias xq after attn
        uint16_t* aol = (uint16_t*)(ws + 4194304);
        uint16_t* woh = wqh;                           // alias wq split after QKV
        uint16_t* wol = wql;

        split_hl<<<dim3(4096), blk, 0, stream>>>(x,  xh,  xl,  1048576);
        split_hl<<<dim3(8192), blk, 0, stream>>>(wq, wqh, wql, 2097152);
        split_hl<<<dim3(2048), blk, 0, stream>>>(wk, wkh, wkl, 524288);
        split_hl<<<dim3(2048), blk, 0, stream>>>(wv, wvh, wvl, 524288);
        gemm_qkv2<<<dim3(768), blk, 0, stream>>>(xh, xl, wqh, wql, wkh, wkl, wvh, wvl, xq, xk, xv);
        split_hl<<<dim3(8192), blk, 0, stream>>>(wo, woh, wol, 2097152);
        rope_k<<<dim3(20480), blk, 0, stream>>>(xq, xk);
        conv_kv<<<dim3(64, 8), blk, 0, stream>>>(xk, xv, kvg);
        attn_mfma<<<dim3(256), dim3(512), 0, stream>>>(xq, kvg, ao);
        split_hl<<<dim3(4096), blk, 0, stream>>>(ao, aoh, aol, 1048576);
        gemm_out2<<<dim3(512), blk, 0, stream>>>(aoh, aol, woh, wol, out);
    } else {
        gemm_hilo<<<dim3(32, 16), blk, 0, stream>>>(x, wq, xq, 2048, 4096, 4096);
        gemm_hilo<<<dim3(8, 16),  blk, 0, stream>>>(x, wk, xk, 2048, 1024, 4096);
        gemm_hilo<<<dim3(8, 16),  blk, 0, stream>>>(x, wv, xv, 2048, 1024, 4096);
        rope_k<<<dim3(20480), blk, 0, stream>>>(xq, xk);
        conv_kv<<<dim3(64, 8), blk, 0, stream>>>(xk, xv, kvg);
        attn_mfma<<<dim3(256), dim3(512), 0, stream>>>(xq, kvg, ao);
        gemm_hilo<<<dim3(32, 16), blk, 0, stream>>>(ao, wo, out, 2048, 4096, 4096);
    }
}

// Round 5
// 817.769 us; speedup vs baseline: 3.5022x; 1.0725x over previous
//
#include <hip/hip_runtime.h>
#include <hip/hip_bf16.h>

typedef __bf16 bf16_t;
typedef unsigned int uint;
typedef __attribute__((ext_vector_type(8))) __bf16 bf16x8;
typedef __attribute__((ext_vector_type(4))) __bf16 bf16x4;
typedef __attribute__((ext_vector_type(4))) float f32x4;
typedef __attribute__((ext_vector_type(16))) float f32x16;

#define LDS_STRIDE 40

// ---------------- repack fp32 [R][4096] -> packed hi/lo bf16 [R/128][128 kb][128 r][32 c] ----------------
// Bank swizzle baked in: elem pos = r*32 + ((slot ^ ((r>>1)&3))<<3) + (c&7), slot = c>>3.
__global__ __launch_bounds__(256) void repack_hl(const float* __restrict__ src,
                                                 uint16_t* __restrict__ dh,
                                                 uint16_t* __restrict__ dl)
{
    const int p  = blockIdx.y;
    const int kb = blockIdx.x;        // 0..127
    const int tid = threadIdx.x;
    const int rr = tid >> 3;          // 0..31
    const int k4 = tid & 7;           // float4 index within the 32-col block
    const int slot = k4 >> 1;
    const int so   = (k4 & 1) * 4;
    uint16_t* bh = dh + ((size_t)p * 128 + kb) * 4096;
    uint16_t* bl = dl + ((size_t)p * 128 + kb) * 4096;
    #pragma unroll
    for (int it = 0; it < 4; ++it) {
        const int r = it * 32 + rr;
        const float4 v = *reinterpret_cast<const float4*>(
            &src[((size_t)p * 128 + r) * 4096 + kb * 32 + k4 * 4]);
        float f[4] = {v.x, v.y, v.z, v.w};
        bf16x4 h, l;
        #pragma unroll
        for (int e = 0; e < 4; ++e) {
            bf16_t hb = (bf16_t)f[e];
            h[e] = hb;
            l[e] = (bf16_t)(f[e] - (float)hb);
        }
        const int pos = r * 32 + ((slot ^ ((r >> 1) & 3)) << 3) + so;
        *reinterpret_cast<bf16x4*>(&bh[pos]) = h;
        *reinterpret_cast<bf16x4*>(&bl[pos]) = l;
    }
}

// ---------------- 128x128 tile GEMM on packed operands, contiguous global_load_lds staging ----------------
// Ah/Al/Bh/Bl point at the tile's panel base (packed). K-step t's chunk = base + t*4096 elems, 8KB contiguous.
__device__ __forceinline__ void tile_mm3(const uint16_t* __restrict__ Ah,
                                         const uint16_t* __restrict__ Al,
                                         const uint16_t* __restrict__ Bh,
                                         const uint16_t* __restrict__ Bl,
                                         int NT, float* __restrict__ Cp, int ldc)
{
    __shared__ char lds[2][32768];

    const int tid  = threadIdx.x;
    const int lane = tid & 63;
    const int w    = tid >> 6;
    const int wr   = (w >> 1) * 64;
    const int wc   = (w & 1) * 64;

    f32x4 acc[4][4] = {};

    const uint16_t* sp[8];
    int dof[8];
    {
        const uint16_t* srcs[4] = {Ah, Al, Bh, Bl};
        #pragma unroll
        for (int a = 0; a < 4; ++a)
            #pragma unroll
            for (int i = 0; i < 2; ++i) {
                sp[a * 2 + i]  = srcs[a] + (size_t)(i * 256 + tid) * 8;
                dof[a * 2 + i] = a * 8192 + (i * 256 + tid) * 16;
            }
    }

    // prologue: stage tile 0
    #pragma unroll
    for (int j = 0; j < 8; ++j)
        __builtin_amdgcn_global_load_lds(
            (const __attribute__((address_space(1))) void*)(sp[j]),
            (__attribute__((address_space(3))) void*)(&lds[0][0] + dof[j]),
            16, 0, 0);
    __syncthreads();

    const int fr = lane & 15;
    const int s4 = lane >> 4;

    for (int t = 0; t < NT; ++t) {
        if (t + 1 < NT) {
            const int kt = (t + 1) * 4096;
            char* nb = &lds[(t + 1) & 1][0];
            #pragma unroll
            for (int j = 0; j < 8; ++j)
                __builtin_amdgcn_global_load_lds(
                    (const __attribute__((address_space(1))) void*)(sp[j] + kt),
                    (__attribute__((address_space(3))) void*)(nb + dof[j]),
                    16, 0, 0);
        }
        const char* b = &lds[t & 1][0];

        bf16x8 fah[4], fal[4], fbh[4], fbl[4];
        #pragma unroll
        for (int i = 0; i < 4; ++i) {
            const int ar = wr + i * 16 + fr;
            const int aoff = ar * 64 + ((s4 ^ ((ar >> 1) & 3)) << 4);
            fah[i] = *reinterpret_cast<const bf16x8*>(b + aoff);
            fal[i] = *reinterpret_cast<const bf16x8*>(b + 8192 + aoff);
            const int br = wc + i * 16 + fr;
            const int boff = br * 64 + ((s4 ^ ((br >> 1) & 3)) << 4);
            fbh[i] = *reinterpret_cast<const bf16x8*>(b + 16384 + boff);
            fbl[i] = *reinterpret_cast<const bf16x8*>(b + 24576 + boff);
        }

        #pragma unroll
        for (int i = 0; i < 4; ++i)
            #pragma unroll
            for (int j = 0; j < 4; ++j) {
                acc[i][j] = __builtin_amdgcn_mfma_f32_16x16x32_bf16(fah[i], fbh[j], acc[i][j], 0, 0, 0);
                acc[i][j] = __builtin_amdgcn_mfma_f32_16x16x32_bf16(fal[i], fbh[j], acc[i][j], 0, 0, 0);
                acc[i][j] = __builtin_amdgcn_mfma_f32_16x16x32_bf16(fah[i], fbl[j], acc[i][j], 0, 0, 0);
            }
        __syncthreads();
    }

    const int crow = wr + ((lane >> 4) << 2);
    const int ccol = wc + (lane & 15);
    #pragma unroll
    for (int i = 0; i < 4; ++i)
        #pragma unroll
        for (int j = 0; j < 4; ++j)
            #pragma unroll
            for (int rr = 0; rr < 4; ++rr)
                Cp[(size_t)(crow + i * 16 + rr) * ldc + ccol + j * 16] = acc[i][j][rr];
}

// Merged QKV projection. grid 768 (1D), XCD-chunked bijective swizzle (768%8==0).
__global__ __launch_bounds__(256) void gemm_qkv3(const uint16_t* __restrict__ xh,  const uint16_t* __restrict__ xl,
                                                 const uint16_t* __restrict__ wqh, const uint16_t* __restrict__ wql,
                                                 const uint16_t* __restrict__ wkh, const uint16_t* __restrict__ wkl,
                                                 const uint16_t* __restrict__ wvh, const uint16_t* __restrict__ wvl,
                                                 float* __restrict__ xq, float* __restrict__ xk, float* __restrict__ xv)
{
    const int bid = blockIdx.x;
    const int swz = (bid & 7) * 96 + (bid >> 3);
    const int by = swz / 48;
    const int bx = swz % 48;
    const uint16_t *Bh, *Bl;
    float* op;
    int ldc, cb;
    if (bx < 32)      { Bh = wqh; Bl = wql; op = xq; ldc = 4096; cb = bx; }
    else if (bx < 40) { Bh = wkh; Bl = wkl; op = xk; ldc = 1024; cb = bx - 32; }
    else              { Bh = wvh; Bl = wvl; op = xv; ldc = 1024; cb = bx - 40; }
    tile_mm3(xh + (size_t)by * 128 * 4096, xl + (size_t)by * 128 * 4096,
             Bh + (size_t)cb * 128 * 4096, Bl + (size_t)cb * 128 * 4096,
             128, op + (size_t)by * 128 * ldc + cb * 128, ldc);
}

// Output projection. grid 512 (1D), XCD swizzle (512%8==0).
__global__ __launch_bounds__(256) void gemm_out3(const uint16_t* __restrict__ ah, const uint16_t* __restrict__ al,
                                                 const uint16_t* __restrict__ bh, const uint16_t* __restrict__ bl,
                                                 float* __restrict__ C)
{
    const int bid = blockIdx.x;
    const int swz = (bid & 7) * 64 + (bid >> 3);
    const int by = swz >> 5;
    const int bx = swz & 31;
    tile_mm3(ah + (size_t)by * 128 * 4096, al + (size_t)by * 128 * 4096,
             bh + (size_t)bx * 128 * 4096, bl + (size_t)bx * 128 * 4096,
             128, C + (size_t)by * 128 * 4096 + bx * 128, 4096);
}

// ---------------- legacy fused-convert GEMM (fallback path if ws too small) ----------------
__global__ __launch_bounds__(256) void gemm_hilo(const float* __restrict__ A,
                                                 const float* __restrict__ B,
                                                 float* __restrict__ C,
                                                 int M, int N, int K)
{
    __shared__ bf16_t sAh[128 * LDS_STRIDE];
    __shared__ bf16_t sAl[128 * LDS_STRIDE];
    __shared__ bf16_t sBh[128 * LDS_STRIDE];
    __shared__ bf16_t sBl[128 * LDS_STRIDE];

    const int tid  = threadIdx.x;
    const int lane = tid & 63;
    const int wave = tid >> 6;
    const int wr   = (wave >> 1) * 64;
    const int wc   = (wave & 1) * 64;
    const int row0 = blockIdx.y * 128;
    const int col0 = blockIdx.x * 128;

    f32x4 acc[4][4] = {};

    const int lrow = tid >> 3;
    const int lcol = (tid & 7) * 4;

    for (int kt = 0; kt < K; kt += 32) {
        #pragma unroll
        for (int p = 0; p < 4; ++p) {
            const int row = p * 32 + lrow;
            const float4 va = *reinterpret_cast<const float4*>(&A[(size_t)(row0 + row) * K + kt + lcol]);
            const float4 vb = *reinterpret_cast<const float4*>(&B[(size_t)(col0 + row) * K + kt + lcol]);
            float fa[4] = {va.x, va.y, va.z, va.w};
            float fb[4] = {vb.x, vb.y, vb.z, vb.w};
            bf16x4 ah, al, bh, bl;
            #pragma unroll
            for (int e = 0; e < 4; ++e) {
                bf16_t hv = (bf16_t)fa[e];
                ah[e] = hv;
                al[e] = (bf16_t)(fa[e] - (float)hv);
                bf16_t g = (bf16_t)fb[e];
                bh[e] = g;
                bl[e] = (bf16_t)(fb[e] - (float)g);
            }
            *reinterpret_cast<bf16x4*>(&sAh[row * LDS_STRIDE + lcol]) = ah;
            *reinterpret_cast<bf16x4*>(&sAl[row * LDS_STRIDE + lcol]) = al;
            *reinterpret_cast<bf16x4*>(&sBh[row * LDS_STRIDE + lcol]) = bh;
            *reinterpret_cast<bf16x4*>(&sBl[row * LDS_STRIDE + lcol]) = bl;
        }
        __syncthreads();

        const int fr = lane & 15;
        const int kc = (lane >> 4) * 8;
        bf16x8 fah[4], fal[4], fbh[4], fbl[4];
        #pragma unroll
        for (int i = 0; i < 4; ++i) {
            const int ar = wr + i * 16 + fr;
            fah[i] = *reinterpret_cast<const bf16x8*>(&sAh[ar * LDS_STRIDE + kc]);
            fal[i] = *reinterpret_cast<const bf16x8*>(&sAl[ar * LDS_STRIDE + kc]);
            const int br = wc + i * 16 + fr;
            fbh[i] = *reinterpret_cast<const bf16x8*>(&sBh[br * LDS_STRIDE + kc]);
            fbl[i] = *reinterpret_cast<const bf16x8*>(&sBl[br * LDS_STRIDE + kc]);
        }

        #pragma unroll
        for (int i = 0; i < 4; ++i)
            #pragma unroll
            for (int j = 0; j < 4; ++j) {
                acc[i][j] = __builtin_amdgcn_mfma_f32_16x16x32_bf16(fah[i], fbh[j], acc[i][j], 0, 0, 0);
                acc[i][j] = __builtin_amdgcn_mfma_f32_16x16x32_bf16(fal[i], fbh[j], acc[i][j], 0, 0, 0);
                acc[i][j] = __builtin_amdgcn_mfma_f32_16x16x32_bf16(fah[i], fbl[j], acc[i][j], 0, 0, 0);
            }
        __syncthreads();
    }

    const int crow = row0 + wr + (lane >> 4) * 4;
    const int ccol = col0 + wc + (lane & 15);
    #pragma unroll
    for (int i = 0; i < 4; ++i)
        #pragma unroll
        for (int j = 0; j < 4; ++j)
            #pragma unroll
            for (int rr = 0; rr < 4; ++rr)
                C[(size_t)(crow + i * 16 + rr) * N + ccol + j * 16] = acc[i][j][rr];
}

// ---------------- RoPE in place; Q additionally scaled by 1/sqrt(128) ----------------
__global__ __launch_bounds__(256) void rope_k(float* __restrict__ xq, float* __restrict__ xk)
{
    const int idx = blockIdx.x * 256 + threadIdx.x;
    const int TOTQ = 2048 * 32 * 64;
    int s, j;
    float* base;
    bool isq = idx < TOTQ;
    if (isq) {
        s = idx >> 11;
        const int rem = idx & 2047;
        j = rem & 63;
        base = xq + (size_t)s * 4096 + (rem >> 6) * 128 + 2 * j;
    } else {
        const int i2 = idx - TOTQ;
        s = i2 >> 9;
        const int rem = i2 & 511;
        j = rem & 63;
        base = xk + (size_t)s * 1024 + (rem >> 6) * 128 + 2 * j;
    }
    const float invf = exp2f(-(float)j * (13.287712379549449f / 64.0f));
    const float ang = (float)s * invf;
    float sn, cs;
    sincosf(ang, &sn, &cs);
    float2 v = *reinterpret_cast<float2*>(base);
    float2 r;
    r.x = v.x * cs - v.y * sn;
    r.y = v.x * sn + v.y * cs;
    if (isq) { r.x *= 0.08838834764831845f; r.y *= 0.08838834764831845f; }
    *reinterpret_cast<float2*>(base) = r;
}

// ---------------- Convert roped K and raw V to blocked+swizzled bf16 hi/lo tiles ----------------
__global__ __launch_bounds__(256) void conv_kv(const float* __restrict__ xk,
                                               const float* __restrict__ xv,
                                               uint16_t* __restrict__ kvg)
{
    __shared__ float V[32][129];
    const int t = blockIdx.x;
    const int h = blockIdx.y;
    const int tid = threadIdx.x;
    uint16_t* tile = kvg + ((size_t)(h * 64 + t)) * 16384;

    #pragma unroll
    for (int i = 0; i < 4; ++i) {
        int v = i * 256 + tid;
        int row = v >> 5, c4 = (v & 31) * 4;
        *reinterpret_cast<float4*>(&V[row][c4]) =
            *reinterpret_cast<const float4*>(&xv[(size_t)(t * 32 + row) * 1024 + h * 128 + c4]);
    }

    {
        const int r = tid >> 3;
        const int d0 = (tid & 7) * 16;
        float f[16];
        const float* kr = &xk[(size_t)(t * 32 + r) * 1024 + h * 128 + d0];
        *reinterpret_cast<float4*>(&f[0])  = *reinterpret_cast<const float4*>(kr);
        *reinterpret_cast<float4*>(&f[4])  = *reinterpret_cast<const float4*>(kr + 4);
        *reinterpret_cast<float4*>(&f[8])  = *reinterpret_cast<const float4*>(kr + 8);
        *reinterpret_cast<float4*>(&f[12]) = *reinterpret_cast<const float4*>(kr + 12);
        #pragma unroll
        for (int cc = 0; cc < 2; ++cc) {
            bf16x8 hv, lv;
            #pragma unroll
            for (int e = 0; e < 8; ++e) {
                float x = f[cc * 8 + e];
                bf16_t hb = (bf16_t)x;
                hv[e] = hb;
                lv[e] = (bf16_t)(x - (float)hb);
            }
            const int c = (d0 >> 3) + cc;
            const int pos = r * 128 + ((c ^ (r & 15)) << 3);
            *reinterpret_cast<bf16x8*>(&tile[pos]) = hv;
            *reinterpret_cast<bf16x8*>(&tile[4096 + pos]) = lv;
        }
    }
    __syncthreads();
    {
        const int d = tid >> 1;
        const int k0 = (tid & 1) * 16;
        float g[16];
        #pragma unroll
        for (int j = 0; j < 16; ++j) g[j] = V[k0 + j][d];
        #pragma unroll
        for (int cc = 0; cc < 2; ++cc) {
            bf16x8 hv, lv;
            #pragma unroll
            for (int e = 0; e < 8; ++e) {
                float x = g[cc * 8 + e];
                bf16_t hb = (bf16_t)x;
                hv[e] = hb;
                lv[e] = (bf16_t)(x - (float)hb);
            }
            const int c = (k0 >> 3) + cc;
            const int pos = d * 32 + ((c ^ (d & 3)) << 3);
            *reinterpret_cast<bf16x8*>(&tile[8192 + pos]) = hv;
            *reinterpret_cast<bf16x8*>(&tile[12288 + pos]) = lv;
        }
    }
}

// ---------------- MFMA flash attention ----------------
__device__ __forceinline__ uint cvtpk(float lo, float hi) {
    uint r;
    asm("v_cvt_pk_bf16_f32 %0, %1, %2" : "=v"(r) : "v"(lo), "v"(hi));
    return r;
}
__device__ __forceinline__ void permswap(uint& a, uint& b) {
    asm("v_permlane32_swap_b32 %0, %1" : "+v"(a), "+v"(b));
}
__device__ __forceinline__ bf16x8 pack4(uint w0, uint w1, uint w2, uint w3) {
    union { uint u[4]; bf16x8 v; } t;
    t.u[0] = w0; t.u[1] = w1; t.u[2] = w2; t.u[3] = w3;
    return t.v;
}

__global__ __launch_bounds__(512, 2) void attn_mfma(const float* __restrict__ xq,
                                                    const uint16_t* __restrict__ kvg,
                                                    float* __restrict__ ao)
{
    __shared__ char lds[2][32768];

    const int b = blockIdx.x;
    const int kvh = b & 7;
    const int r = b >> 3;
    const int h = kvh * 4 + (r & 3);
    const int q0 = (r >> 2) * 256;
    const int tid = threadIdx.x;
    const int w = tid >> 6;
    const int lane = tid & 63;
    const int ln31 = lane & 31;
    const int hi = lane >> 5;

    const int q = q0 + w * 32 + ln31;
    const float* qrow = xq + (size_t)q * 4096 + h * 128;
    bf16x8 Qh[8], Ql[8];
    #pragma unroll
    for (int ks = 0; ks < 8; ++ks) {
        float f[8];
        *reinterpret_cast<float4*>(&f[0]) = *reinterpret_cast<const float4*>(qrow + ks * 16 + hi * 8);
        *reinterpret_cast<float4*>(&f[4]) = *reinterpret_cast<const float4*>(qrow + ks * 16 + hi * 8 + 4);
        #pragma unroll
        for (int e = 0; e < 8; ++e) {
            bf16_t hb = (bf16_t)f[e];
            Qh[ks][e] = hb;
            Ql[ks][e] = (bf16_t)(f[e] - (float)hb);
        }
    }

    const char* gkv = (const char*)kvg + (size_t)kvh * 64 * 32768;

    f32x16 oacc[4] = {{}, {}, {}, {}};
    float m = -3.0e38f, l = 0.f;

    {
        const char* g = gkv;
        #pragma unroll
        for (int i = 0; i < 4; ++i) {
            const int chunk = i * 8 + w;
            __builtin_amdgcn_global_load_lds(
                (const __attribute__((address_space(1))) void*)(g + chunk * 1024 + lane * 16),
                (__attribute__((address_space(3))) void*)(&lds[0][chunk * 1024]),
                16, 0, 0);
        }
    }

    for (int t = 0; t < 64; ++t) {
        __syncthreads();
        if (t + 1 < 64) {
            const char* g = gkv + (size_t)(t + 1) * 32768;
            const int buf = (t + 1) & 1;
            #pragma unroll
            for (int i = 0; i < 4; ++i) {
                const int chunk = i * 8 + w;
                __builtin_amdgcn_global_load_lds(
                    (const __attribute__((address_space(1))) void*)(g + chunk * 1024 + lane * 16),
                    (__attribute__((address_space(3))) void*)(&lds[buf][chunk * 1024]),
                    16, 0, 0);
            }
        }
        const int cur = t & 1;
        const char* Kh = lds[cur];
        const char* Kl = lds[cur] + 8192;
        const char* Vh = lds[cur] + 16384;
        const char* Vl = lds[cur] + 24576;

        f32x16 s = {};
        #pragma unroll
        for (int ks = 0; ks < 8; ++ks) {
            const int row = ln31;
            const int byt = row * 256 + ((ks * 32 + hi * 16) ^ ((row & 15) << 4));
            bf16x8 ah = *reinterpret_cast<const bf16x8*>(Kh + byt);
            bf16x8 al = *reinterpret_cast<const bf16x8*>(Kl + byt);
            s = __builtin_amdgcn_mfma_f32_32x32x16_bf16(ah, Qh[ks], s, 0, 0, 0);
            s = __builtin_amdgcn_mfma_f32_32x32x16_bf16(al, Qh[ks], s, 0, 0, 0);
            s = __builtin_amdgcn_mfma_f32_32x32x16_bf16(ah, Ql[ks], s, 0, 0, 0);
        }

        float mx = s[0];
        #pragma unroll
        for (int jj = 1; jj < 16; ++jj) mx = fmaxf(mx, s[jj]);
        mx = fmaxf(mx, __shfl_xor(mx, 32));
        const float mnew = fmaxf(m, mx);
        const float corr = __expf(m - mnew);
        m = mnew;
        float psum = 0.f;
        #pragma unroll
        for (int jj = 0; jj < 16; ++jj) {
            float pv = __expf(s[jj] - m);
            s[jj] = pv;
            psum += pv;
        }
        psum += __shfl_xor(psum, 32);
        l = l * corr + psum;
        #pragma unroll
        for (int dt = 0; dt < 4; ++dt) oacc[dt] *= corr;

        #pragma unroll
        for (int ks = 0; ks < 2; ++ks) {
            const int b0 = ks * 8;
            uint wa = cvtpk(s[b0 + 0], s[b0 + 1]);
            uint wb = cvtpk(s[b0 + 2], s[b0 + 3]);
            uint wc = cvtpk(s[b0 + 4], s[b0 + 5]);
            uint wd = cvtpk(s[b0 + 6], s[b0 + 7]);
            float r0 = s[b0 + 0] - __uint_as_float(wa << 16);
            float r1 = s[b0 + 1] - __uint_as_float(wa & 0xffff0000u);
            float r2 = s[b0 + 2] - __uint_as_float(wb << 16);
            float r3 = s[b0 + 3] - __uint_as_float(wb & 0xffff0000u);
            float r4 = s[b0 + 4] - __uint_as_float(wc << 16);
            float r5 = s[b0 + 5] - __uint_as_float(wc & 0xffff0000u);
            float r6 = s[b0 + 6] - __uint_as_float(wd << 16);
            float r7 = s[b0 + 7] - __uint_as_float(wd & 0xffff0000u);
            uint la = cvtpk(r0, r1);
            uint lb = cvtpk(r2, r3);
            uint lc = cvtpk(r4, r5);
            uint ld = cvtpk(r6, r7);
            permswap(wa, wc); permswap(wb, wd);
            permswap(la, lc); permswap(lb, ld);
            bf16x8 Pf  = pack4(wa, wb, wc, wd);
            bf16x8 Plf = pack4(la, lb, lc, ld);
            #pragma unroll
            for (int dt = 0; dt < 4; ++dt) {
                const int row = dt * 32 + ln31;
                const int byt = row * 64 + ((ks * 32 + hi * 16) ^ ((row & 3) << 4));
                bf16x8 vh = *reinterpret_cast<const bf16x8*>(Vh + byt);
                bf16x8 vl = *reinterpret_cast<const bf16x8*>(Vl + byt);
                oacc[dt] = __builtin_amdgcn_mfma_f32_32x32x16_bf16(vh, Pf,  oacc[dt], 0, 0, 0);
                oacc[dt] = __builtin_amdgcn_mfma_f32_32x32x16_bf16(vh, Plf, oacc[dt], 0, 0, 0);
                oacc[dt] = __builtin_amdgcn_mfma_f32_32x32x16_bf16(vl, Pf,  oacc[dt], 0, 0, 0);
            }
        }
    }

    const float invl = 1.0f / l;
    float* aorow = ao + (size_t)q * 4096 + h * 128;
    #pragma unroll
    for (int dt = 0; dt < 4; ++dt)
        #pragma unroll
        for (int g4 = 0; g4 < 4; ++g4) {
            float4 v;
            v.x = oacc[dt][g4 * 4 + 0] * invl;
            v.y = oacc[dt][g4 * 4 + 1] * invl;
            v.z = oacc[dt][g4 * 4 + 2] * invl;
            v.w = oacc[dt][g4 * 4 + 3] * invl;
            *reinterpret_cast<float4*>(aorow + dt * 32 + 8 * g4 + 4 * hi) = v;
        }
}

extern "C" void kernel_launch(void* const* d_in, const int* in_sizes, int n_in,
                              void* d_out, int out_size, void* d_ws, size_t ws_size,
                              hipStream_t stream)
{
    const float* x  = (const float*)d_in[0];
    const float* wq = (const float*)d_in[1];
    const float* wk = (const float*)d_in[2];
    const float* wv = (const float*)d_in[3];
    const float* wo = (const float*)d_in[4];
    float* out = (float*)d_out;

    float* ws = (float*)d_ws;
    float*    xq  = ws;                          // [0, 8388608)
    uint16_t* kvg = (uint16_t*)(ws + 8388608);   // [8388608, 12582912)
    float*    xk  = ws + 12582912;               // [12582912, 14680064)
    float*    xv  = ws + 14680064;               // [14680064, 16777216)
    float*    ao  = ws + 12582912;               // aliases xk/xv after conv_kv

    dim3 blk(256);
    const size_t NEED = (size_t)54525952 * 4;

    if (ws_size >= NEED) {
        uint16_t* xh  = (uint16_t*)(ws + 20971520);
        uint16_t* xl  = (uint16_t*)(ws + 25165824);
        uint16_t* wqh = (uint16_t*)(ws + 29360128);
        uint16_t* wql = (uint16_t*)(ws + 37748736);
        uint16_t* wkh = (uint16_t*)(ws + 46137344);
        uint16_t* wkl = (uint16_t*)(ws + 48234496);
        uint16_t* wvh = (uint16_t*)(ws + 50331648);
        uint16_t* wvl = (uint16_t*)(ws + 52428800);
        uint16_t* aoh = (uint16_t*)(ws);              // alias xq after attn
        uint16_t* aol = (uint16_t*)(ws + 4194304);
        uint16_t* woh = wqh;                           // alias wq split after QKV
        uint16_t* wol = wql;

        repack_hl<<<dim3(128, 16), blk, 0, stream>>>(x,  xh,  xl);
        repack_hl<<<dim3(128, 32), blk, 0, stream>>>(wq, wqh, wql);
        repack_hl<<<dim3(128, 8),  blk, 0, stream>>>(wk, wkh, wkl);
        repack_hl<<<dim3(128, 8),  blk, 0, stream>>>(wv, wvh, wvl);
        gemm_qkv3<<<dim3(768), blk, 0, stream>>>(xh, xl, wqh, wql, wkh, wkl, wvh, wvl, xq, xk, xv);
        repack_hl<<<dim3(128, 32), blk, 0, stream>>>(wo, woh, wol);
        rope_k<<<dim3(20480), blk, 0, stream>>>(xq, xk);
        conv_kv<<<dim3(64, 8), blk, 0, stream>>>(xk, xv, kvg);
        attn_mfma<<<dim3(256), dim3(512), 0, stream>>>(xq, kvg, ao);
        repack_hl<<<dim3(128, 16), blk, 0, stream>>>(ao, aoh, aol);
        gemm_out3<<<dim3(512), blk, 0, stream>>>(aoh, aol, woh, wol, out);
    } else {
        gemm_hilo<<<dim3(32, 16), blk, 0, stream>>>(x, wq, xq, 2048, 4096, 4096);
        gemm_hilo<<<dim3(8, 16),  blk, 0, stream>>>(x, wk, xk, 2048, 1024, 4096);
        gemm_hilo<<<dim3(8, 16),  blk, 0, stream>>>(x, wv, xv, 2048, 1024, 4096);
        rope_k<<<dim3(20480), blk, 0, stream>>>(xq, xk);
        conv_kv<<<dim3(64, 8), blk, 0, stream>>>(xk, xv, kvg);
        attn_mfma<<<dim3(256), dim3(512), 0, stream>>>(xq, kvg, ao);
        gemm_hilo<<<dim3(32, 16), blk, 0, stream>>>(ao, wo, out, 2048, 4096, 4096);
    }
}

// Round 6
// 654.412 us; speedup vs baseline: 4.3764x; 1.2496x over previous
//
#include <hip/hip_runtime.h>
#include <hip/hip_bf16.h>

typedef __bf16 bf16_t;
typedef unsigned int uint;
typedef __attribute__((ext_vector_type(8))) __bf16 bf16x8;
typedef __attribute__((ext_vector_type(4))) __bf16 bf16x4;
typedef __attribute__((ext_vector_type(4))) float f32x4;
typedef __attribute__((ext_vector_type(16))) float f32x16;

#define LDS_STRIDE 40

// ---------------- repack fp32 [R][4096] -> packed hi/lo bf16 [R/128][128 kb][128 r][32 c] ----------------
// Bank swizzle baked in: elem pos = r*32 + ((slot ^ ((r>>1)&3))<<3) + (c&7), slot = c>>3.
__global__ __launch_bounds__(256) void repack_hl(const float* __restrict__ src,
                                                 uint16_t* __restrict__ dh,
                                                 uint16_t* __restrict__ dl)
{
    const int p  = blockIdx.y;
    const int kb = blockIdx.x;        // 0..127
    const int tid = threadIdx.x;
    const int rr = tid >> 3;          // 0..31
    const int k4 = tid & 7;           // float4 index within the 32-col block
    const int slot = k4 >> 1;
    const int so   = (k4 & 1) * 4;
    uint16_t* bh = dh + ((size_t)p * 128 + kb) * 4096;
    uint16_t* bl = dl + ((size_t)p * 128 + kb) * 4096;
    #pragma unroll
    for (int it = 0; it < 4; ++it) {
        const int r = it * 32 + rr;
        const float4 v = *reinterpret_cast<const float4*>(
            &src[((size_t)p * 128 + r) * 4096 + kb * 32 + k4 * 4]);
        float f[4] = {v.x, v.y, v.z, v.w};
        bf16x4 h, l;
        #pragma unroll
        for (int e = 0; e < 4; ++e) {
            bf16_t hb = (bf16_t)f[e];
            h[e] = hb;
            l[e] = (bf16_t)(f[e] - (float)hb);
        }
        const int pos = r * 32 + ((slot ^ ((r >> 1) & 3)) << 3) + so;
        *reinterpret_cast<bf16x4*>(&bh[pos]) = h;
        *reinterpret_cast<bf16x4*>(&bl[pos]) = l;
    }
}

// hi-only variant for weights (B operand needs no lo in the 2-pass scheme)
__global__ __launch_bounds__(256) void repack_h(const float* __restrict__ src,
                                                uint16_t* __restrict__ dh)
{
    const int p  = blockIdx.y;
    const int kb = blockIdx.x;
    const int tid = threadIdx.x;
    const int rr = tid >> 3;
    const int k4 = tid & 7;
    const int slot = k4 >> 1;
    const int so   = (k4 & 1) * 4;
    uint16_t* bh = dh + ((size_t)p * 128 + kb) * 4096;
    #pragma unroll
    for (int it = 0; it < 4; ++it) {
        const int r = it * 32 + rr;
        const float4 v = *reinterpret_cast<const float4*>(
            &src[((size_t)p * 128 + r) * 4096 + kb * 32 + k4 * 4]);
        float f[4] = {v.x, v.y, v.z, v.w};
        bf16x4 h;
        #pragma unroll
        for (int e = 0; e < 4; ++e) h[e] = (bf16_t)f[e];
        const int pos = r * 32 + ((slot ^ ((r >> 1) & 3)) << 3) + so;
        *reinterpret_cast<bf16x4*>(&bh[pos]) = h;
    }
}

// ---------------- 128x128 tile GEMM on packed operands, 2-pass (AhBh + AlBh) ----------------
// Ah/Al/Bh point at the tile's panel base (packed). K-step t's chunk = base + t*4096 elems, 8KB contiguous.
__device__ __forceinline__ void tile_mm3(const uint16_t* __restrict__ Ah,
                                         const uint16_t* __restrict__ Al,
                                         const uint16_t* __restrict__ Bh,
                                         int NT, float* __restrict__ Cp, int ldc)
{
    __shared__ char lds[2][24576];

    const int tid  = threadIdx.x;
    const int lane = tid & 63;
    const int w    = tid >> 6;
    const int wr   = (w >> 1) * 64;
    const int wc   = (w & 1) * 64;

    f32x4 acc[4][4] = {};

    const uint16_t* sp[6];
    int dof[6];
    {
        const uint16_t* srcs[3] = {Ah, Al, Bh};
        #pragma unroll
        for (int a = 0; a < 3; ++a)
            #pragma unroll
            for (int i = 0; i < 2; ++i) {
                sp[a * 2 + i]  = srcs[a] + (size_t)(i * 256 + tid) * 8;
                dof[a * 2 + i] = a * 8192 + (i * 256 + tid) * 16;
            }
    }

    // prologue: stage tile 0
    #pragma unroll
    for (int j = 0; j < 6; ++j)
        __builtin_amdgcn_global_load_lds(
            (const __attribute__((address_space(1))) void*)(sp[j]),
            (__attribute__((address_space(3))) void*)(&lds[0][0] + dof[j]),
            16, 0, 0);
    __syncthreads();

    const int fr = lane & 15;
    const int s4 = lane >> 4;

    for (int t = 0; t < NT; ++t) {
        if (t + 1 < NT) {
            const int kt = (t + 1) * 4096;
            char* nb = &lds[(t + 1) & 1][0];
            #pragma unroll
            for (int j = 0; j < 6; ++j)
                __builtin_amdgcn_global_load_lds(
                    (const __attribute__((address_space(1))) void*)(sp[j] + kt),
                    (__attribute__((address_space(3))) void*)(nb + dof[j]),
                    16, 0, 0);
        }
        const char* b = &lds[t & 1][0];

        bf16x8 fah[4], fal[4], fbh[4];
        #pragma unroll
        for (int i = 0; i < 4; ++i) {
            const int ar = wr + i * 16 + fr;
            const int aoff = ar * 64 + ((s4 ^ ((ar >> 1) & 3)) << 4);
            fah[i] = *reinterpret_cast<const bf16x8*>(b + aoff);
            fal[i] = *reinterpret_cast<const bf16x8*>(b + 8192 + aoff);
            const int br = wc + i * 16 + fr;
            const int boff = br * 64 + ((s4 ^ ((br >> 1) & 3)) << 4);
            fbh[i] = *reinterpret_cast<const bf16x8*>(b + 16384 + boff);
        }

        #pragma unroll
        for (int i = 0; i < 4; ++i)
            #pragma unroll
            for (int j = 0; j < 4; ++j) {
                acc[i][j] = __builtin_amdgcn_mfma_f32_16x16x32_bf16(fah[i], fbh[j], acc[i][j], 0, 0, 0);
                acc[i][j] = __builtin_amdgcn_mfma_f32_16x16x32_bf16(fal[i], fbh[j], acc[i][j], 0, 0, 0);
            }
        __syncthreads();
    }

    const int crow = wr + ((lane >> 4) << 2);
    const int ccol = wc + (lane & 15);
    #pragma unroll
    for (int i = 0; i < 4; ++i)
        #pragma unroll
        for (int j = 0; j < 4; ++j)
            #pragma unroll
            for (int rr = 0; rr < 4; ++rr)
                Cp[(size_t)(crow + i * 16 + rr) * ldc + ccol + j * 16] = acc[i][j][rr];
}

// Merged QKV projection. grid 768 (1D), XCD-chunked bijective swizzle (768%8==0).
__global__ __launch_bounds__(256) void gemm_qkv3(const uint16_t* __restrict__ xh,  const uint16_t* __restrict__ xl,
                                                 const uint16_t* __restrict__ wqh,
                                                 const uint16_t* __restrict__ wkh,
                                                 const uint16_t* __restrict__ wvh,
                                                 float* __restrict__ xq, float* __restrict__ xk, float* __restrict__ xv)
{
    const int bid = blockIdx.x;
    const int swz = (bid & 7) * 96 + (bid >> 3);
    const int by = swz / 48;
    const int bx = swz % 48;
    const uint16_t *Bh;
    float* op;
    int ldc, cb;
    if (bx < 32)      { Bh = wqh; op = xq; ldc = 4096; cb = bx; }
    else if (bx < 40) { Bh = wkh; op = xk; ldc = 1024; cb = bx - 32; }
    else              { Bh = wvh; op = xv; ldc = 1024; cb = bx - 40; }
    tile_mm3(xh + (size_t)by * 128 * 4096, xl + (size_t)by * 128 * 4096,
             Bh + (size_t)cb * 128 * 4096,
             128, op + (size_t)by * 128 * ldc + cb * 128, ldc);
}

// Output projection. grid 512 (1D), XCD swizzle (512%8==0).
__global__ __launch_bounds__(256) void gemm_out3(const uint16_t* __restrict__ ah, const uint16_t* __restrict__ al,
                                                 const uint16_t* __restrict__ bh,
                                                 float* __restrict__ C)
{
    const int bid = blockIdx.x;
    const int swz = (bid & 7) * 64 + (bid >> 3);
    const int by = swz >> 5;
    const int bx = swz & 31;
    tile_mm3(ah + (size_t)by * 128 * 4096, al + (size_t)by * 128 * 4096,
             bh + (size_t)bx * 128 * 4096,
             128, C + (size_t)by * 128 * 4096 + bx * 128, 4096);
}

// ---------------- legacy fused-convert GEMM (fallback path if ws too small) ----------------
__global__ __launch_bounds__(256) void gemm_hilo(const float* __restrict__ A,
                                                 const float* __restrict__ B,
                                                 float* __restrict__ C,
                                                 int M, int N, int K)
{
    __shared__ bf16_t sAh[128 * LDS_STRIDE];
    __shared__ bf16_t sAl[128 * LDS_STRIDE];
    __shared__ bf16_t sBh[128 * LDS_STRIDE];
    __shared__ bf16_t sBl[128 * LDS_STRIDE];

    const int tid  = threadIdx.x;
    const int lane = tid & 63;
    const int wave = tid >> 6;
    const int wr   = (wave >> 1) * 64;
    const int wc   = (wave & 1) * 64;
    const int row0 = blockIdx.y * 128;
    const int col0 = blockIdx.x * 128;

    f32x4 acc[4][4] = {};

    const int lrow = tid >> 3;
    const int lcol = (tid & 7) * 4;

    for (int kt = 0; kt < K; kt += 32) {
        #pragma unroll
        for (int p = 0; p < 4; ++p) {
            const int row = p * 32 + lrow;
            const float4 va = *reinterpret_cast<const float4*>(&A[(size_t)(row0 + row) * K + kt + lcol]);
            const float4 vb = *reinterpret_cast<const float4*>(&B[(size_t)(col0 + row) * K + kt + lcol]);
            float fa[4] = {va.x, va.y, va.z, va.w};
            float fb[4] = {vb.x, vb.y, vb.z, vb.w};
            bf16x4 ah, al, bh, bl;
            #pragma unroll
            for (int e = 0; e < 4; ++e) {
                bf16_t hv = (bf16_t)fa[e];
                ah[e] = hv;
                al[e] = (bf16_t)(fa[e] - (float)hv);
                bf16_t g = (bf16_t)fb[e];
                bh[e] = g;
                bl[e] = (bf16_t)(fb[e] - (float)g);
            }
            *reinterpret_cast<bf16x4*>(&sAh[row * LDS_STRIDE + lcol]) = ah;
            *reinterpret_cast<bf16x4*>(&sAl[row * LDS_STRIDE + lcol]) = al;
            *reinterpret_cast<bf16x4*>(&sBh[row * LDS_STRIDE + lcol]) = bh;
            *reinterpret_cast<bf16x4*>(&sBl[row * LDS_STRIDE + lcol]) = bl;
        }
        __syncthreads();

        const int fr = lane & 15;
        const int kc = (lane >> 4) * 8;
        bf16x8 fah[4], fal[4], fbh[4], fbl[4];
        #pragma unroll
        for (int i = 0; i < 4; ++i) {
            const int ar = wr + i * 16 + fr;
            fah[i] = *reinterpret_cast<const bf16x8*>(&sAh[ar * LDS_STRIDE + kc]);
            fal[i] = *reinterpret_cast<const bf16x8*>(&sAl[ar * LDS_STRIDE + kc]);
            const int br = wc + i * 16 + fr;
            fbh[i] = *reinterpret_cast<const bf16x8*>(&sBh[br * LDS_STRIDE + kc]);
            fbl[i] = *reinterpret_cast<const bf16x8*>(&sBl[br * LDS_STRIDE + kc]);
        }

        #pragma unroll
        for (int i = 0; i < 4; ++i)
            #pragma unroll
            for (int j = 0; j < 4; ++j) {
                acc[i][j] = __builtin_amdgcn_mfma_f32_16x16x32_bf16(fah[i], fbh[j], acc[i][j], 0, 0, 0);
                acc[i][j] = __builtin_amdgcn_mfma_f32_16x16x32_bf16(fal[i], fbh[j], acc[i][j], 0, 0, 0);
                acc[i][j] = __builtin_amdgcn_mfma_f32_16x16x32_bf16(fah[i], fbl[j], acc[i][j], 0, 0, 0);
            }
        __syncthreads();
    }

    const int crow = row0 + wr + (lane >> 4) * 4;
    const int ccol = col0 + wc + (lane & 15);
    #pragma unroll
    for (int i = 0; i < 4; ++i)
        #pragma unroll
        for (int j = 0; j < 4; ++j)
            #pragma unroll
            for (int rr = 0; rr < 4; ++rr)
                C[(size_t)(crow + i * 16 + rr) * N + ccol + j * 16] = acc[i][j][rr];
}

// ---------------- RoPE in place; Q additionally scaled by 1/sqrt(128) ----------------
__global__ __launch_bounds__(256) void rope_k(float* __restrict__ xq, float* __restrict__ xk)
{
    const int idx = blockIdx.x * 256 + threadIdx.x;
    const int TOTQ = 2048 * 32 * 64;
    int s, j;
    float* base;
    bool isq = idx < TOTQ;
    if (isq) {
        s = idx >> 11;
        const int rem = idx & 2047;
        j = rem & 63;
        base = xq + (size_t)s * 4096 + (rem >> 6) * 128 + 2 * j;
    } else {
        const int i2 = idx - TOTQ;
        s = i2 >> 9;
        const int rem = i2 & 511;
        j = rem & 63;
        base = xk + (size_t)s * 1024 + (rem >> 6) * 128 + 2 * j;
    }
    const float invf = exp2f(-(float)j * (13.287712379549449f / 64.0f));
    const float ang = (float)s * invf;
    float sn, cs;
    sincosf(ang, &sn, &cs);
    float2 v = *reinterpret_cast<float2*>(base);
    float2 r;
    r.x = v.x * cs - v.y * sn;
    r.y = v.x * sn + v.y * cs;
    if (isq) { r.x *= 0.08838834764831845f; r.y *= 0.08838834764831845f; }
    *reinterpret_cast<float2*>(base) = r;
}

// ---------------- Convert roped K and raw V to blocked+swizzled bf16 hi/lo tiles ----------------
__global__ __launch_bounds__(256) void conv_kv(const float* __restrict__ xk,
                                               const float* __restrict__ xv,
                                               uint16_t* __restrict__ kvg)
{
    __shared__ float V[32][129];
    const int t = blockIdx.x;
    const int h = blockIdx.y;
    const int tid = threadIdx.x;
    uint16_t* tile = kvg + ((size_t)(h * 64 + t)) * 16384;

    #pragma unroll
    for (int i = 0; i < 4; ++i) {
        int v = i * 256 + tid;
        int row = v >> 5, c4 = (v & 31) * 4;
        *reinterpret_cast<float4*>(&V[row][c4]) =
            *reinterpret_cast<const float4*>(&xv[(size_t)(t * 32 + row) * 1024 + h * 128 + c4]);
    }

    {
        const int r = tid >> 3;
        const int d0 = (tid & 7) * 16;
        float f[16];
        const float* kr = &xk[(size_t)(t * 32 + r) * 1024 + h * 128 + d0];
        *reinterpret_cast<float4*>(&f[0])  = *reinterpret_cast<const float4*>(kr);
        *reinterpret_cast<float4*>(&f[4])  = *reinterpret_cast<const float4*>(kr + 4);
        *reinterpret_cast<float4*>(&f[8])  = *reinterpret_cast<const float4*>(kr + 8);
        *reinterpret_cast<float4*>(&f[12]) = *reinterpret_cast<const float4*>(kr + 12);
        #pragma unroll
        for (int cc = 0; cc < 2; ++cc) {
            bf16x8 hv, lv;
            #pragma unroll
            for (int e = 0; e < 8; ++e) {
                float x = f[cc * 8 + e];
                bf16_t hb = (bf16_t)x;
                hv[e] = hb;
                lv[e] = (bf16_t)(x - (float)hb);
            }
            const int c = (d0 >> 3) + cc;
            const int pos = r * 128 + ((c ^ (r & 15)) << 3);
            *reinterpret_cast<bf16x8*>(&tile[pos]) = hv;
            *reinterpret_cast<bf16x8*>(&tile[4096 + pos]) = lv;
        }
    }
    __syncthreads();
    {
        const int d = tid >> 1;
        const int k0 = (tid & 1) * 16;
        float g[16];
        #pragma unroll
        for (int j = 0; j < 16; ++j) g[j] = V[k0 + j][d];
        #pragma unroll
        for (int cc = 0; cc < 2; ++cc) {
            bf16x8 hv, lv;
            #pragma unroll
            for (int e = 0; e < 8; ++e) {
                float x = g[cc * 8 + e];
                bf16_t hb = (bf16_t)x;
                hv[e] = hb;
                lv[e] = (bf16_t)(x - (float)hb);
            }
            const int c = (k0 >> 3) + cc;
            const int pos = d * 32 + ((c ^ (d & 3)) << 3);
            *reinterpret_cast<bf16x8*>(&tile[8192 + pos]) = hv;
            *reinterpret_cast<bf16x8*>(&tile[12288 + pos]) = lv;
        }
    }
}

// ---------------- MFMA flash attention ----------------
__device__ __forceinline__ uint cvtpk(float lo, float hi) {
    uint r;
    asm("v_cvt_pk_bf16_f32 %0, %1, %2" : "=v"(r) : "v"(lo), "v"(hi));
    return r;
}
__device__ __forceinline__ void permswap(uint& a, uint& b) {
    asm("v_permlane32_swap_b32 %0, %1" : "+v"(a), "+v"(b));
}
__device__ __forceinline__ bf16x8 pack4(uint w0, uint w1, uint w2, uint w3) {
    union { uint u[4]; bf16x8 v; } t;
    t.u[0] = w0; t.u[1] = w1; t.u[2] = w2; t.u[3] = w3;
    return t.v;
}

__global__ __launch_bounds__(512, 2) void attn_mfma(const float* __restrict__ xq,
                                                    const uint16_t* __restrict__ kvg,
                                                    float* __restrict__ ao)
{
    __shared__ char lds[2][32768];

    const int b = blockIdx.x;
    const int kvh = b & 7;
    const int r = b >> 3;
    const int h = kvh * 4 + (r & 3);
    const int q0 = (r >> 2) * 256;
    const int tid = threadIdx.x;
    const int w = tid >> 6;
    const int lane = tid & 63;
    const int ln31 = lane & 31;
    const int hi = lane >> 5;

    const int q = q0 + w * 32 + ln31;
    const float* qrow = xq + (size_t)q * 4096 + h * 128;
    bf16x8 Qh[8], Ql[8];
    #pragma unroll
    for (int ks = 0; ks < 8; ++ks) {
        float f[8];
        *reinterpret_cast<float4*>(&f[0]) = *reinterpret_cast<const float4*>(qrow + ks * 16 + hi * 8);
        *reinterpret_cast<float4*>(&f[4]) = *reinterpret_cast<const float4*>(qrow + ks * 16 + hi * 8 + 4);
        #pragma unroll
        for (int e = 0; e < 8; ++e) {
            bf16_t hb = (bf16_t)f[e];
            Qh[ks][e] = hb;
            Ql[ks][e] = (bf16_t)(f[e] - (float)hb);
        }
    }

    const char* gkv = (const char*)kvg + (size_t)kvh * 64 * 32768;

    f32x16 oacc[4] = {{}, {}, {}, {}};
    float m = -3.0e38f, l = 0.f;

    {
        const char* g = gkv;
        #pragma unroll
        for (int i = 0; i < 4; ++i) {
            const int chunk = i * 8 + w;
            __builtin_amdgcn_global_load_lds(
                (const __attribute__((address_space(1))) void*)(g + chunk * 1024 + lane * 16),
                (__attribute__((address_space(3))) void*)(&lds[0][chunk * 1024]),
                16, 0, 0);
        }
    }

    for (int t = 0; t < 64; ++t) {
        __syncthreads();
        if (t + 1 < 64) {
            const char* g = gkv + (size_t)(t + 1) * 32768;
            const int buf = (t + 1) & 1;
            #pragma unroll
            for (int i = 0; i < 4; ++i) {
                const int chunk = i * 8 + w;
                __builtin_amdgcn_global_load_lds(
                    (const __attribute__((address_space(1))) void*)(g + chunk * 1024 + lane * 16),
                    (__attribute__((address_space(3))) void*)(&lds[buf][chunk * 1024]),
                    16, 0, 0);
            }
        }
        const int cur = t & 1;
        const char* Kh = lds[cur];
        const char* Kl = lds[cur] + 8192;
        const char* Vh = lds[cur] + 16384;
        const char* Vl = lds[cur] + 24576;

        f32x16 s = {};
        #pragma unroll
        for (int ks = 0; ks < 8; ++ks) {
            const int row = ln31;
            const int byt = row * 256 + ((ks * 32 + hi * 16) ^ ((row & 15) << 4));
            bf16x8 ah = *reinterpret_cast<const bf16x8*>(Kh + byt);
            bf16x8 al = *reinterpret_cast<const bf16x8*>(Kl + byt);
            s = __builtin_amdgcn_mfma_f32_32x32x16_bf16(ah, Qh[ks], s, 0, 0, 0);
            s = __builtin_amdgcn_mfma_f32_32x32x16_bf16(al, Qh[ks], s, 0, 0, 0);
            s = __builtin_amdgcn_mfma_f32_32x32x16_bf16(ah, Ql[ks], s, 0, 0, 0);
        }

        float mx = s[0];
        #pragma unroll
        for (int jj = 1; jj < 16; ++jj) mx = fmaxf(mx, s[jj]);
        mx = fmaxf(mx, __shfl_xor(mx, 32));
        const float mnew = fmaxf(m, mx);
        const float corr = __expf(m - mnew);
        m = mnew;
        float psum = 0.f;
        #pragma unroll
        for (int jj = 0; jj < 16; ++jj) {
            float pv = __expf(s[jj] - m);
            s[jj] = pv;
            psum += pv;
        }
        psum += __shfl_xor(psum, 32);
        l = l * corr + psum;
        #pragma unroll
        for (int dt = 0; dt < 4; ++dt) oacc[dt] *= corr;

        #pragma unroll
        for (int ks = 0; ks < 2; ++ks) {
            const int b0 = ks * 8;
            uint wa = cvtpk(s[b0 + 0], s[b0 + 1]);
            uint wb = cvtpk(s[b0 + 2], s[b0 + 3]);
            uint wc = cvtpk(s[b0 + 4], s[b0 + 5]);
            uint wd = cvtpk(s[b0 + 6], s[b0 + 7]);
            float r0 = s[b0 + 0] - __uint_as_float(wa << 16);
            float r1 = s[b0 + 1] - __uint_as_float(wa & 0xffff0000u);
            float r2 = s[b0 + 2] - __uint_as_float(wb << 16);
            float r3 = s[b0 + 3] - __uint_as_float(wb & 0xffff0000u);
            float r4 = s[b0 + 4] - __uint_as_float(wc << 16);
            float r5 = s[b0 + 5] - __uint_as_float(wc & 0xffff0000u);
            float r6 = s[b0 + 6] - __uint_as_float(wd << 16);
            float r7 = s[b0 + 7] - __uint_as_float(wd & 0xffff0000u);
            uint la = cvtpk(r0, r1);
            uint lb = cvtpk(r2, r3);
            uint lc = cvtpk(r4, r5);
            uint ld = cvtpk(r6, r7);
            permswap(wa, wc); permswap(wb, wd);
            permswap(la, lc); permswap(lb, ld);
            bf16x8 Pf  = pack4(wa, wb, wc, wd);
            bf16x8 Plf = pack4(la, lb, lc, ld);
            #pragma unroll
            for (int dt = 0; dt < 4; ++dt) {
                const int row = dt * 32 + ln31;
                const int byt = row * 64 + ((ks * 32 + hi * 16) ^ ((row & 3) << 4));
                bf16x8 vh = *reinterpret_cast<const bf16x8*>(Vh + byt);
                bf16x8 vl = *reinterpret_cast<const bf16x8*>(Vl + byt);
                oacc[dt] = __builtin_amdgcn_mfma_f32_32x32x16_bf16(vh, Pf,  oacc[dt], 0, 0, 0);
                oacc[dt] = __builtin_amdgcn_mfma_f32_32x32x16_bf16(vh, Plf, oacc[dt], 0, 0, 0);
                oacc[dt] = __builtin_amdgcn_mfma_f32_32x32x16_bf16(vl, Pf,  oacc[dt], 0, 0, 0);
            }
        }
    }

    const float invl = 1.0f / l;
    float* aorow = ao + (size_t)q * 4096 + h * 128;
    #pragma unroll
    for (int dt = 0; dt < 4; ++dt)
        #pragma unroll
        for (int g4 = 0; g4 < 4; ++g4) {
            float4 v;
            v.x = oacc[dt][g4 * 4 + 0] * invl;
            v.y = oacc[dt][g4 * 4 + 1] * invl;
            v.z = oacc[dt][g4 * 4 + 2] * invl;
            v.w = oacc[dt][g4 * 4 + 3] * invl;
            *reinterpret_cast<float4*>(aorow + dt * 32 + 8 * g4 + 4 * hi) = v;
        }
}

extern "C" void kernel_launch(void* const* d_in, const int* in_sizes, int n_in,
                              void* d_out, int out_size, void* d_ws, size_t ws_size,
                              hipStream_t stream)
{
    const float* x  = (const float*)d_in[0];
    const float* wq = (const float*)d_in[1];
    const float* wk = (const float*)d_in[2];
    const float* wv = (const float*)d_in[3];
    const float* wo = (const float*)d_in[4];
    float* out = (float*)d_out;

    float* ws = (float*)d_ws;
    float*    xq  = ws;                          // [0, 8388608)
    uint16_t* kvg = (uint16_t*)(ws + 8388608);   // [8388608, 12582912)
    float*    xk  = ws + 12582912;               // [12582912, 14680064)
    float*    xv  = ws + 14680064;               // [14680064, 16777216)
    float*    ao  = ws + 12582912;               // aliases xk/xv after conv_kv

    dim3 blk(256);
    const size_t NEED = (size_t)54525952 * 4;

    if (ws_size >= NEED) {
        uint16_t* xh  = (uint16_t*)(ws + 20971520);
        uint16_t* xl  = (uint16_t*)(ws + 25165824);
        uint16_t* wqh = (uint16_t*)(ws + 29360128);   // 16.8M elems (hi only)
        uint16_t* wkh = (uint16_t*)(ws + 46137344);
        uint16_t* wvh = (uint16_t*)(ws + 50331648);
        uint16_t* aoh = (uint16_t*)(ws);              // alias xq after attn
        uint16_t* aol = (uint16_t*)(ws + 4194304);
        uint16_t* woh = wqh;                           // alias wq-hi slot after QKV

        repack_hl<<<dim3(128, 16), blk, 0, stream>>>(x,  xh,  xl);
        repack_h <<<dim3(128, 32), blk, 0, stream>>>(wq, wqh);
        repack_h <<<dim3(128, 8),  blk, 0, stream>>>(wk, wkh);
        repack_h <<<dim3(128, 8),  blk, 0, stream>>>(wv, wvh);
        gemm_qkv3<<<dim3(768), blk, 0, stream>>>(xh, xl, wqh, wkh, wvh, xq, xk, xv);
        repack_h <<<dim3(128, 32), blk, 0, stream>>>(wo, woh);
        rope_k<<<dim3(20480), blk, 0, stream>>>(xq, xk);
        conv_kv<<<dim3(64, 8), blk, 0, stream>>>(xk, xv, kvg);
        attn_mfma<<<dim3(256), dim3(512), 0, stream>>>(xq, kvg, ao);
        repack_hl<<<dim3(128, 16), blk, 0, stream>>>(ao, aoh, aol);
        gemm_out3<<<dim3(512), blk, 0, stream>>>(aoh, aol, woh, out);
    } else {
        gemm_hilo<<<dim3(32, 16), blk, 0, stream>>>(x, wq, xq, 2048, 4096, 4096);
        gemm_hilo<<<dim3(8, 16),  blk, 0, stream>>>(x, wk, xk, 2048, 1024, 4096);
        gemm_hilo<<<dim3(8, 16),  blk, 0, stream>>>(x, wv, xv, 2048, 1024, 4096);
        rope_k<<<dim3(20480), blk, 0, stream>>>(xq, xk);
        conv_kv<<<dim3(64, 8), blk, 0, stream>>>(xk, xv, kvg);
        attn_mfma<<<dim3(256), dim3(512), 0, stream>>>(xq, kvg, ao);
        gemm_hilo<<<dim3(32, 16), blk, 0, stream>>>(ao, wo, out, 2048, 4096, 4096);
    }
}

// Round 7
// 572.340 us; speedup vs baseline: 5.0040x; 1.1434x over previous
//
#include <hip/hip_runtime.h>
#include <hip/hip_bf16.h>

typedef __bf16 bf16_t;
typedef unsigned int uint;
typedef __attribute__((ext_vector_type(8))) __bf16 bf16x8;
typedef __attribute__((ext_vector_type(4))) __bf16 bf16x4;
typedef __attribute__((ext_vector_type(4))) float f32x4;
typedef __attribute__((ext_vector_type(16))) float f32x16;

// ---------------- repack fp32 [R][4096] -> packed hi/lo bf16 [R/128][128 kb][128 r][32 c] ----------------
// Bank swizzle baked in: elem pos = r*32 + ((slot ^ ((r>>1)&3))<<3) + (c&7), slot = c>>3.
__global__ __launch_bounds__(256) void repack_hl(const float* __restrict__ src,
                                                 uint16_t* __restrict__ dh,
                                                 uint16_t* __restrict__ dl)
{
    const int p  = blockIdx.y;
    const int kb = blockIdx.x;        // 0..127
    const int tid = threadIdx.x;
    const int rr = tid >> 3;          // 0..31
    const int k4 = tid & 7;           // float4 index within the 32-col block
    const int slot = k4 >> 1;
    const int so   = (k4 & 1) * 4;
    uint16_t* bh = dh + ((size_t)p * 128 + kb) * 4096;
    uint16_t* bl = dl + ((size_t)p * 128 + kb) * 4096;
    #pragma unroll
    for (int it = 0; it < 4; ++it) {
        const int r = it * 32 + rr;
        const float4 v = *reinterpret_cast<const float4*>(
            &src[((size_t)p * 128 + r) * 4096 + kb * 32 + k4 * 4]);
        float f[4] = {v.x, v.y, v.z, v.w};
        bf16x4 h, l;
        #pragma unroll
        for (int e = 0; e < 4; ++e) {
            bf16_t hb = (bf16_t)f[e];
            h[e] = hb;
            l[e] = (bf16_t)(f[e] - (float)hb);
        }
        const int pos = r * 32 + ((slot ^ ((r >> 1) & 3)) << 3) + so;
        *reinterpret_cast<bf16x4*>(&bh[pos]) = h;
        *reinterpret_cast<bf16x4*>(&bl[pos]) = l;
    }
}

// hi-only variant for weights (B operand needs no lo in the 2-pass scheme)
__global__ __launch_bounds__(256) void repack_h(const float* __restrict__ src,
                                                uint16_t* __restrict__ dh)
{
    const int p  = blockIdx.y;
    const int kb = blockIdx.x;
    const int tid = threadIdx.x;
    const int rr = tid >> 3;
    const int k4 = tid & 7;
    const int slot = k4 >> 1;
    const int so   = (k4 & 1) * 4;
    uint16_t* bh = dh + ((size_t)p * 128 + kb) * 4096;
    #pragma unroll
    for (int it = 0; it < 4; ++it) {
        const int r = it * 32 + rr;
        const float4 v = *reinterpret_cast<const float4*>(
            &src[((size_t)p * 128 + r) * 4096 + kb * 32 + k4 * 4]);
        float f[4] = {v.x, v.y, v.z, v.w};
        bf16x4 h;
        #pragma unroll
        for (int e = 0; e < 4; ++e) h[e] = (bf16_t)f[e];
        const int pos = r * 32 + ((slot ^ ((r >> 1) & 3)) << 3) + so;
        *reinterpret_cast<bf16x4*>(&bh[pos]) = h;
    }
}

// ---------------- 128x128 tile GEMM on packed operands, 2-pass (AhBh + AlBh) ----------------
__device__ __forceinline__ void tile_mm3(const uint16_t* __restrict__ Ah,
                                         const uint16_t* __restrict__ Al,
                                         const uint16_t* __restrict__ Bh,
                                         int NT, float* __restrict__ Cp, int ldc)
{
    __shared__ char lds[2][24576];

    const int tid  = threadIdx.x;
    const int lane = tid & 63;
    const int w    = tid >> 6;
    const int wr   = (w >> 1) * 64;
    const int wc   = (w & 1) * 64;

    f32x4 acc[4][4] = {};

    const uint16_t* sp[6];
    int dof[6];
    {
        const uint16_t* srcs[3] = {Ah, Al, Bh};
        #pragma unroll
        for (int a = 0; a < 3; ++a)
            #pragma unroll
            for (int i = 0; i < 2; ++i) {
                sp[a * 2 + i]  = srcs[a] + (size_t)(i * 256 + tid) * 8;
                dof[a * 2 + i] = a * 8192 + (i * 256 + tid) * 16;
            }
    }

    #pragma unroll
    for (int j = 0; j < 6; ++j)
        __builtin_amdgcn_global_load_lds(
            (const __attribute__((address_space(1))) void*)(sp[j]),
            (__attribute__((address_space(3))) void*)(&lds[0][0] + dof[j]),
            16, 0, 0);
    __syncthreads();

    const int fr = lane & 15;
    const int s4 = lane >> 4;

    for (int t = 0; t < NT; ++t) {
        if (t + 1 < NT) {
            const int kt = (t + 1) * 4096;
            char* nb = &lds[(t + 1) & 1][0];
            #pragma unroll
            for (int j = 0; j < 6; ++j)
                __builtin_amdgcn_global_load_lds(
                    (const __attribute__((address_space(1))) void*)(sp[j] + kt),
                    (__attribute__((address_space(3))) void*)(nb + dof[j]),
                    16, 0, 0);
        }
        const char* b = &lds[t & 1][0];

        bf16x8 fah[4], fal[4], fbh[4];
        #pragma unroll
        for (int i = 0; i < 4; ++i) {
            const int ar = wr + i * 16 + fr;
            const int aoff = ar * 64 + ((s4 ^ ((ar >> 1) & 3)) << 4);
            fah[i] = *reinterpret_cast<const bf16x8*>(b + aoff);
            fal[i] = *reinterpret_cast<const bf16x8*>(b + 8192 + aoff);
            const int br = wc + i * 16 + fr;
            const int boff = br * 64 + ((s4 ^ ((br >> 1) & 3)) << 4);
            fbh[i] = *reinterpret_cast<const bf16x8*>(b + 16384 + boff);
        }

        #pragma unroll
        for (int i = 0; i < 4; ++i)
            #pragma unroll
            for (int j = 0; j < 4; ++j) {
                acc[i][j] = __builtin_amdgcn_mfma_f32_16x16x32_bf16(fah[i], fbh[j], acc[i][j], 0, 0, 0);
                acc[i][j] = __builtin_amdgcn_mfma_f32_16x16x32_bf16(fal[i], fbh[j], acc[i][j], 0, 0, 0);
            }
        __syncthreads();
    }

    const int crow = wr + ((lane >> 4) << 2);
    const int ccol = wc + (lane & 15);
    #pragma unroll
    for (int i = 0; i < 4; ++i)
        #pragma unroll
        for (int j = 0; j < 4; ++j)
            #pragma unroll
            for (int rr = 0; rr < 4; ++rr)
                Cp[(size_t)(crow + i * 16 + rr) * ldc + ccol + j * 16] = acc[i][j][rr];
}

// Merged QKV projection. grid 768 (1D), XCD-chunked bijective swizzle (768%8==0).
__global__ __launch_bounds__(256) void gemm_qkv3(const uint16_t* __restrict__ xh,  const uint16_t* __restrict__ xl,
                                                 const uint16_t* __restrict__ wqh,
                                                 const uint16_t* __restrict__ wkh,
                                                 const uint16_t* __restrict__ wvh,
                                                 float* __restrict__ xq, float* __restrict__ xk, float* __restrict__ xv)
{
    const int bid = blockIdx.x;
    const int swz = (bid & 7) * 96 + (bid >> 3);
    const int by = swz / 48;
    const int bx = swz % 48;
    const uint16_t *Bh;
    float* op;
    int ldc, cb;
    if (bx < 32)      { Bh = wqh; op = xq; ldc = 4096; cb = bx; }
    else if (bx < 40) { Bh = wkh; op = xk; ldc = 1024; cb = bx - 32; }
    else              { Bh = wvh; op = xv; ldc = 1024; cb = bx - 40; }
    tile_mm3(xh + (size_t)by * 128 * 4096, xl + (size_t)by * 128 * 4096,
             Bh + (size_t)cb * 128 * 4096,
             128, op + (size_t)by * 128 * ldc + cb * 128, ldc);
}

// Output projection. grid 512 (1D), XCD swizzle (512%8==0).
__global__ __launch_bounds__(256) void gemm_out3(const uint16_t* __restrict__ ah, const uint16_t* __restrict__ al,
                                                 const uint16_t* __restrict__ bh,
                                                 float* __restrict__ C)
{
    const int bid = blockIdx.x;
    const int swz = (bid & 7) * 64 + (bid >> 3);
    const int by = swz >> 5;
    const int bx = swz & 31;
    tile_mm3(ah + (size_t)by * 128 * 4096, al + (size_t)by * 128 * 4096,
             bh + (size_t)bx * 128 * 4096,
             128, C + (size_t)by * 128 * 4096 + bx * 128, 4096);
}

// ---------------- RoPE in place; Q additionally scaled by 1/sqrt(128) ----------------
__global__ __launch_bounds__(256) void rope_k(float* __restrict__ xq, float* __restrict__ xk)
{
    const int idx = blockIdx.x * 256 + threadIdx.x;
    const int TOTQ = 2048 * 32 * 64;
    int s, j;
    float* base;
    bool isq = idx < TOTQ;
    if (isq) {
        s = idx >> 11;
        const int rem = idx & 2047;
        j = rem & 63;
        base = xq + (size_t)s * 4096 + (rem >> 6) * 128 + 2 * j;
    } else {
        const int i2 = idx - TOTQ;
        s = i2 >> 9;
        const int rem = i2 & 511;
        j = rem & 63;
        base = xk + (size_t)s * 1024 + (rem >> 6) * 128 + 2 * j;
    }
    const float invf = exp2f(-(float)j * (13.287712379549449f / 64.0f));
    const float ang = (float)s * invf;
    float sn, cs;
    sincosf(ang, &sn, &cs);
    float2 v = *reinterpret_cast<float2*>(base);
    float2 r;
    r.x = v.x * cs - v.y * sn;
    r.y = v.x * sn + v.y * cs;
    if (isq) { r.x *= 0.08838834764831845f; r.y *= 0.08838834764831845f; }
    *reinterpret_cast<float2*>(base) = r;
}

// ---------------- Convert roped K (hi+lo) and raw V (hi only) to blocked+swizzled bf16 tiles ----------------
// Tile = 12288 uint16 (24 KB): Kh[32 kv][128 d] at 0, Kl at 4096, Vth[128 d][32 kv] at 8192.
__global__ __launch_bounds__(256) void conv_kv(const float* __restrict__ xk,
                                               const float* __restrict__ xv,
                                               uint16_t* __restrict__ kvg)
{
    __shared__ float V[32][129];
    const int t = blockIdx.x;
    const int h = blockIdx.y;
    const int tid = threadIdx.x;
    uint16_t* tile = kvg + ((size_t)(h * 64 + t)) * 12288;

    #pragma unroll
    for (int i = 0; i < 4; ++i) {
        int v = i * 256 + tid;
        int row = v >> 5, c4 = (v & 31) * 4;
        *reinterpret_cast<float4*>(&V[row][c4]) =
            *reinterpret_cast<const float4*>(&xv[(size_t)(t * 32 + row) * 1024 + h * 128 + c4]);
    }

    {
        const int r = tid >> 3;
        const int d0 = (tid & 7) * 16;
        float f[16];
        const float* kr = &xk[(size_t)(t * 32 + r) * 1024 + h * 128 + d0];
        *reinterpret_cast<float4*>(&f[0])  = *reinterpret_cast<const float4*>(kr);
        *reinterpret_cast<float4*>(&f[4])  = *reinterpret_cast<const float4*>(kr + 4);
        *reinterpret_cast<float4*>(&f[8])  = *reinterpret_cast<const float4*>(kr + 8);
        *reinterpret_cast<float4*>(&f[12]) = *reinterpret_cast<const float4*>(kr + 12);
        #pragma unroll
        for (int cc = 0; cc < 2; ++cc) {
            bf16x8 hv, lv;
            #pragma unroll
            for (int e = 0; e < 8; ++e) {
                float x = f[cc * 8 + e];
                bf16_t hb = (bf16_t)x;
                hv[e] = hb;
                lv[e] = (bf16_t)(x - (float)hb);
            }
            const int c = (d0 >> 3) + cc;
            const int pos = r * 128 + ((c ^ (r & 15)) << 3);
            *reinterpret_cast<bf16x8*>(&tile[pos]) = hv;
            *reinterpret_cast<bf16x8*>(&tile[4096 + pos]) = lv;
        }
    }
    __syncthreads();
    {
        const int d = tid >> 1;
        const int k0 = (tid & 1) * 16;
        float g[16];
        #pragma unroll
        for (int j = 0; j < 16; ++j) g[j] = V[k0 + j][d];
        #pragma unroll
        for (int cc = 0; cc < 2; ++cc) {
            bf16x8 hv;
            #pragma unroll
            for (int e = 0; e < 8; ++e) hv[e] = (bf16_t)g[cc * 8 + e];
            const int c = (k0 >> 3) + cc;
            const int pos = d * 32 + ((c ^ (d & 3)) << 3);
            *reinterpret_cast<bf16x8*>(&tile[8192 + pos]) = hv;
        }
    }
}

// ---------------- MFMA flash attention (2-pass QK, 1-pass PV, defer-max, fused packed epilogue) ----------------
__device__ __forceinline__ uint cvtpk(float lo, float hi) {
    uint r;
    asm("v_cvt_pk_bf16_f32 %0, %1, %2" : "=v"(r) : "v"(lo), "v"(hi));
    return r;
}
__device__ __forceinline__ void permswap(uint& a, uint& b) {
    asm("v_permlane32_swap_b32 %0, %1" : "+v"(a), "+v"(b));
}
__device__ __forceinline__ bf16x8 pack4(uint w0, uint w1, uint w2, uint w3) {
    union { uint u[4]; bf16x8 v; } t;
    t.u[0] = w0; t.u[1] = w1; t.u[2] = w2; t.u[3] = w3;
    return t.v;
}

__global__ __launch_bounds__(512, 2) void attn_mfma(const float* __restrict__ xq,
                                                    const uint16_t* __restrict__ kvg,
                                                    uint16_t* __restrict__ aoh,
                                                    uint16_t* __restrict__ aol)
{
    __shared__ char lds[2][24576];

    const int b = blockIdx.x;
    const int kvh = b & 7;
    const int r = b >> 3;
    const int h = kvh * 4 + (r & 3);
    const int q0 = (r >> 2) * 256;
    const int tid = threadIdx.x;
    const int w = tid >> 6;
    const int lane = tid & 63;
    const int ln31 = lane & 31;
    const int hi = lane >> 5;

    // ---- Q hi fragments only (2-pass QK: Kh*Qh + Kl*Qh) ----
    const int q = q0 + w * 32 + ln31;
    const float* qrow = xq + (size_t)q * 4096 + h * 128;
    bf16x8 Qh[8];
    #pragma unroll
    for (int ks = 0; ks < 8; ++ks) {
        float f[8];
        *reinterpret_cast<float4*>(&f[0]) = *reinterpret_cast<const float4*>(qrow + ks * 16 + hi * 8);
        *reinterpret_cast<float4*>(&f[4]) = *reinterpret_cast<const float4*>(qrow + ks * 16 + hi * 8 + 4);
        #pragma unroll
        for (int e = 0; e < 8; ++e) Qh[ks][e] = (bf16_t)f[e];
    }

    const char* gkv = (const char*)kvg + (size_t)kvh * 64 * 24576;

    f32x16 oacc[4] = {{}, {}, {}, {}};
    float m = -3.0e38f, l = 0.f;

    {
        #pragma unroll
        for (int i = 0; i < 3; ++i) {
            const int chunk = i * 8 + w;
            __builtin_amdgcn_global_load_lds(
                (const __attribute__((address_space(1))) void*)(gkv + chunk * 1024 + lane * 16),
                (__attribute__((address_space(3))) void*)(&lds[0][chunk * 1024]),
                16, 0, 0);
        }
    }

    for (int t = 0; t < 64; ++t) {
        __syncthreads();
        if (t + 1 < 64) {
            const char* g = gkv + (size_t)(t + 1) * 24576;
            const int buf = (t + 1) & 1;
            #pragma unroll
            for (int i = 0; i < 3; ++i) {
                const int chunk = i * 8 + w;
                __builtin_amdgcn_global_load_lds(
                    (const __attribute__((address_space(1))) void*)(g + chunk * 1024 + lane * 16),
                    (__attribute__((address_space(3))) void*)(&lds[buf][chunk * 1024]),
                    16, 0, 0);
            }
        }
        const int cur = t & 1;
        const char* Kh = lds[cur];
        const char* Kl = lds[cur] + 8192;
        const char* Vh = lds[cur] + 16384;

        // ---- swapped QK^T: S^T[kv][q], 2-pass hi/lo on K ----
        f32x16 s = {};
        __builtin_amdgcn_s_setprio(1);
        #pragma unroll
        for (int ks = 0; ks < 8; ++ks) {
            const int byt = ln31 * 256 + ((ks * 32 + hi * 16) ^ ((ln31 & 15) << 4));
            bf16x8 ah = *reinterpret_cast<const bf16x8*>(Kh + byt);
            bf16x8 al = *reinterpret_cast<const bf16x8*>(Kl + byt);
            s = __builtin_amdgcn_mfma_f32_32x32x16_bf16(ah, Qh[ks], s, 0, 0, 0);
            s = __builtin_amdgcn_mfma_f32_32x32x16_bf16(al, Qh[ks], s, 0, 0, 0);
        }
        __builtin_amdgcn_s_setprio(0);

        // ---- online softmax with defer-max (T13, THR=8) ----
        float pmax = s[0];
        #pragma unroll
        for (int jj = 1; jj < 16; ++jj) pmax = fmaxf(pmax, s[jj]);
        pmax = fmaxf(pmax, __shfl_xor(pmax, 32));
        if (!__all(pmax - m <= 8.0f)) {
            const float mnew = fmaxf(m, pmax);
            const float corr = __expf(m - mnew);
            l *= corr;
            #pragma unroll
            for (int dt = 0; dt < 4; ++dt) oacc[dt] *= corr;
            m = mnew;
        }
        float psum = 0.f;
        #pragma unroll
        for (int jj = 0; jj < 16; ++jj) {
            float pv = __expf(s[jj] - m);
            s[jj] = pv;
            psum += pv;
        }
        psum += __shfl_xor(psum, 32);
        l += psum;

        // ---- P -> bf16 B-fragments (hi only) + 1-pass PV ----
        #pragma unroll
        for (int ks = 0; ks < 2; ++ks) {
            const int b0 = ks * 8;
            uint wa = cvtpk(s[b0 + 0], s[b0 + 1]);
            uint wb = cvtpk(s[b0 + 2], s[b0 + 3]);
            uint wc = cvtpk(s[b0 + 4], s[b0 + 5]);
            uint wd = cvtpk(s[b0 + 6], s[b0 + 7]);
            permswap(wa, wc); permswap(wb, wd);
            bf16x8 Pf = pack4(wa, wb, wc, wd);
            __builtin_amdgcn_s_setprio(1);
            #pragma unroll
            for (int dt = 0; dt < 4; ++dt) {
                const int row = dt * 32 + ln31;
                const int byt = row * 64 + ((ks * 32 + hi * 16) ^ ((row & 3) << 4));
                bf16x8 vh = *reinterpret_cast<const bf16x8*>(Vh + byt);
                oacc[dt] = __builtin_amdgcn_mfma_f32_32x32x16_bf16(vh, Pf, oacc[dt], 0, 0, 0);
            }
            __builtin_amdgcn_s_setprio(0);
        }
    }

    // ---- fused epilogue: O -> hi/lo bf16 directly into packed layout for gemm_out3 ----
    const float invl = 1.0f / l;
    const int p   = q >> 7;
    const int rr_ = q & 127;
    const int rsw = (rr_ >> 1) & 3;
    #pragma unroll
    for (int dt = 0; dt < 4; ++dt) {
        const int kb = h * 4 + dt;
        uint16_t* bh = aoh + ((size_t)p * 128 + kb) * 4096;
        uint16_t* bl = aol + ((size_t)p * 128 + kb) * 4096;
        #pragma unroll
        for (int g4 = 0; g4 < 4; ++g4) {
            bf16x4 hv, lv;
            #pragma unroll
            for (int e = 0; e < 4; ++e) {
                float v = oacc[dt][g4 * 4 + e] * invl;
                bf16_t hb = (bf16_t)v;
                hv[e] = hb;
                lv[e] = (bf16_t)(v - (float)hb);
            }
            const int pos = rr_ * 32 + ((g4 ^ rsw) << 3) + 4 * hi;
            *reinterpret_cast<bf16x4*>(&bh[pos]) = hv;
            *reinterpret_cast<bf16x4*>(&bl[pos]) = lv;
        }
    }
}

extern "C" void kernel_launch(void* const* d_in, const int* in_sizes, int n_in,
                              void* d_out, int out_size, void* d_ws, size_t ws_size,
                              hipStream_t stream)
{
    const float* x  = (const float*)d_in[0];
    const float* wq = (const float*)d_in[1];
    const float* wk = (const float*)d_in[2];
    const float* wv = (const float*)d_in[3];
    const float* wo = (const float*)d_in[4];
    float* out = (float*)d_out;

    float* ws = (float*)d_ws;
    // float-slot offsets (ws >= 218 MB, verified rounds 3-6)
    float*    xq  = ws;                           // [0, 8388608)      fp32 Q (roped)
    uint16_t* kvg = (uint16_t*)(ws + 8388608);    // [8388608, 11534336) packed K/V tiles (12.6 MB)
    float*    xk  = ws + 12582912;                // [12582912, 14680064)
    float*    xv  = ws + 14680064;                // [14680064, 16777216)
    uint16_t* aoh = (uint16_t*)(ws + 12582912);   // reuses xk slot after conv_kv
    uint16_t* aol = (uint16_t*)(ws + 16777216);
    uint16_t* xh  = (uint16_t*)(ws + 20971520);
    uint16_t* xl  = (uint16_t*)(ws + 25165824);
    uint16_t* wqh = (uint16_t*)(ws + 29360128);
    uint16_t* wkh = (uint16_t*)(ws + 46137344);
    uint16_t* wvh = (uint16_t*)(ws + 50331648);
    uint16_t* woh = wqh;                           // reuse wq-hi slot after QKV GEMM

    dim3 blk(256);
    repack_hl<<<dim3(128, 16), blk, 0, stream>>>(x,  xh,  xl);
    repack_h <<<dim3(128, 32), blk, 0, stream>>>(wq, wqh);
    repack_h <<<dim3(128, 8),  blk, 0, stream>>>(wk, wkh);
    repack_h <<<dim3(128, 8),  blk, 0, stream>>>(wv, wvh);
    gemm_qkv3<<<dim3(768), blk, 0, stream>>>(xh, xl, wqh, wkh, wvh, xq, xk, xv);
    repack_h <<<dim3(128, 32), blk, 0, stream>>>(wo, woh);
    rope_k<<<dim3(20480), blk, 0, stream>>>(xq, xk);
    conv_kv<<<dim3(64, 8), blk, 0, stream>>>(xk, xv, kvg);
    attn_mfma<<<dim3(256), dim3(512), 0, stream>>>(xq, kvg, aoh, aol);
    gemm_out3<<<dim3(512), blk, 0, stream>>>(aoh, aol, woh, out);
}

// Round 8
// 513.398 us; speedup vs baseline: 5.5784x; 1.1148x over previous
//
#include <hip/hip_runtime.h>
#include <hip/hip_bf16.h>

typedef __bf16 bf16_t;
typedef unsigned int uint;
typedef __attribute__((ext_vector_type(8))) __bf16 bf16x8;
typedef __attribute__((ext_vector_type(4))) __bf16 bf16x4;
typedef __attribute__((ext_vector_type(4))) float f32x4;
typedef __attribute__((ext_vector_type(16))) float f32x16;

// ---------------- repack fp32 [R][4096] -> packed hi/lo bf16 [R/128][128 kb][128 r][32 c] ----------------
// Bank swizzle baked in: elem pos = r*32 + ((slot ^ ((r>>1)&3))<<3) + (c&7), slot = c>>3.
__global__ __launch_bounds__(256) void repack_hl(const float* __restrict__ src,
                                                 uint16_t* __restrict__ dh,
                                                 uint16_t* __restrict__ dl)
{
    const int p  = blockIdx.y;
    const int kb = blockIdx.x;
    const int tid = threadIdx.x;
    const int rr = tid >> 3;
    const int k4 = tid & 7;
    const int slot = k4 >> 1;
    const int so   = (k4 & 1) * 4;
    uint16_t* bh = dh + ((size_t)p * 128 + kb) * 4096;
    uint16_t* bl = dl + ((size_t)p * 128 + kb) * 4096;
    #pragma unroll
    for (int it = 0; it < 4; ++it) {
        const int r = it * 32 + rr;
        const float4 v = *reinterpret_cast<const float4*>(
            &src[((size_t)p * 128 + r) * 4096 + kb * 32 + k4 * 4]);
        float f[4] = {v.x, v.y, v.z, v.w};
        bf16x4 h, l;
        #pragma unroll
        for (int e = 0; e < 4; ++e) {
            bf16_t hb = (bf16_t)f[e];
            h[e] = hb;
            l[e] = (bf16_t)(f[e] - (float)hb);
        }
        const int pos = r * 32 + ((slot ^ ((r >> 1) & 3)) << 3) + so;
        *reinterpret_cast<bf16x4*>(&bh[pos]) = h;
        *reinterpret_cast<bf16x4*>(&bl[pos]) = l;
    }
}

// hi-only 128-row-panel repack (wo)
__global__ __launch_bounds__(256) void repack_h(const float* __restrict__ src,
                                                uint16_t* __restrict__ dh)
{
    const int p  = blockIdx.y;
    const int kb = blockIdx.x;
    const int tid = threadIdx.x;
    const int rr = tid >> 3;
    const int k4 = tid & 7;
    const int slot = k4 >> 1;
    const int so   = (k4 & 1) * 4;
    uint16_t* bh = dh + ((size_t)p * 128 + kb) * 4096;
    #pragma unroll
    for (int it = 0; it < 4; ++it) {
        const int r = it * 32 + rr;
        const float4 v = *reinterpret_cast<const float4*>(
            &src[((size_t)p * 128 + r) * 4096 + kb * 32 + k4 * 4]);
        float f[4] = {v.x, v.y, v.z, v.w};
        bf16x4 h;
        #pragma unroll
        for (int e = 0; e < 4; ++e) h[e] = (bf16_t)f[e];
        const int pos = r * 32 + ((slot ^ ((r >> 1) & 3)) << 3) + so;
        *reinterpret_cast<bf16x4*>(&bh[pos]) = h;
    }
}

// combined wq|wk|wv -> 96-row-panel packed hi: [64 pan][128 kb][96 r][32 c], per-kb chunk 3072 elems
__global__ __launch_bounds__(256) void repack_w96(const float* __restrict__ wq,
                                                  const float* __restrict__ wk,
                                                  const float* __restrict__ wv,
                                                  uint16_t* __restrict__ dst)
{
    const int kb  = blockIdx.x;   // 0..127
    const int pan = blockIdx.y;   // 0..63
    const int tid = threadIdx.x;
    const int k4 = tid & 7;
    const int slot = k4 >> 1;
    const int so   = (k4 & 1) * 4;
    uint16_t* bh = dst + ((size_t)pan * 128 + kb) * 3072;
    #pragma unroll
    for (int it = 0; it < 3; ++it) {
        const int r = it * 32 + (tid >> 3);      // 0..95
        const int n = pan * 96 + r;
        const float* srow = (n < 4096) ? (wq + (size_t)n * 4096)
                          : (n < 5120) ? (wk + (size_t)(n - 4096) * 4096)
                                       : (wv + (size_t)(n - 5120) * 4096);
        const float4 v = *reinterpret_cast<const float4*>(srow + kb * 32 + k4 * 4);
        float f[4] = {v.x, v.y, v.z, v.w};
        bf16x4 h;
        #pragma unroll
        for (int e = 0; e < 4; ++e) h[e] = (bf16_t)f[e];
        const int pos = r * 32 + ((slot ^ ((r >> 1) & 3)) << 3) + so;
        *reinterpret_cast<bf16x4*>(&bh[pos]) = h;
    }
}

// ---------------- QKV GEMM: 256x192 tile, 8 waves, BK=32, 3-buf depth-2 pipeline, counted vmcnt ----------------
__global__ __launch_bounds__(512) void gemm_qkv4(const uint16_t* __restrict__ xh,
                                                 const uint16_t* __restrict__ xl,
                                                 const uint16_t* __restrict__ wqkv,
                                                 float* __restrict__ xq,
                                                 float* __restrict__ xk,
                                                 float* __restrict__ xv)
{
    __shared__ char lds[3][45056];   // per buf: Ah 16K | Al 16K | Bh 12K

    const int bid = blockIdx.x;
    const int swz = (bid & 7) * 32 + (bid >> 3);   // 256 blocks, XCD-chunked
    const int by = swz >> 5;                        // 0..7
    const int bx = swz & 31;                        // 0..31
    const int tid = threadIdx.x;
    const int w = tid >> 6, lane = tid & 63;
    const int wm = w >> 2, wn = w & 3;
    const int fr = lane & 15, s4 = lane >> 4;

    // stage chunks: c = w + 8i. c<16: Ah, c<32: Al, else Bh (12 chunks). waves 0-3: 6 chunks, 4-7: 5.
    const int cw = (w < 4) ? 6 : 5;
    const uint16_t* sp[6];
    int dof[6];
    int stridec[6];
    #pragma unroll
    for (int i = 0; i < 6; ++i) {
        const int c = w + 8 * i;
        dof[i] = c * 1024;
        if (i < 4) {
            const uint16_t* base = (c < 16) ? xh : xl;
            const int cc = c & 15;
            sp[i] = base + (size_t)(2 * by + (cc >> 3)) * 524288 + (cc & 7) * 512 + lane * 8;
            stridec[i] = 4096;
        } else {
            const int cb = c - 32;
            sp[i] = wqkv + (size_t)(bx * 2 + (cb >= 6 ? 1 : 0)) * 393216 + (cb % 6) * 512 + lane * 8;
            stridec[i] = 3072;
        }
    }

    f32x4 acc[8][3] = {};

    // prologue: stage tiles 0,1
    #pragma unroll
    for (int i = 0; i < 6; ++i)
        if (i < cw)
            __builtin_amdgcn_global_load_lds(
                (const __attribute__((address_space(1))) void*)(sp[i]),
                (__attribute__((address_space(3))) void*)(&lds[0][0] + dof[i]), 16, 0, 0);
    #pragma unroll
    for (int i = 0; i < 6; ++i)
        if (i < cw)
            __builtin_amdgcn_global_load_lds(
                (const __attribute__((address_space(1))) void*)(sp[i] + stridec[i]),
                (__attribute__((address_space(3))) void*)(&lds[1][0] + dof[i]), 16, 0, 0);
    if (w < 4) asm volatile("s_waitcnt vmcnt(6)" ::: "memory");
    else       asm volatile("s_waitcnt vmcnt(5)" ::: "memory");
    __builtin_amdgcn_s_barrier();
    __builtin_amdgcn_sched_barrier(0);

    int cur = 0;
    for (int t = 0; t < 128; ++t) {
        if (t + 2 < 128) {
            int nb = cur + 2; if (nb >= 3) nb -= 3;
            #pragma unroll
            for (int i = 0; i < 6; ++i)
                if (i < cw)
                    __builtin_amdgcn_global_load_lds(
                        (const __attribute__((address_space(1))) void*)(sp[i] + (size_t)(t + 2) * stridec[i]),
                        (__attribute__((address_space(3))) void*)(&lds[nb][0] + dof[i]), 16, 0, 0);
        }
        const char* b = &lds[cur][0];

        bf16x8 fb[3];
        #pragma unroll
        for (int j = 0; j < 3; ++j) {
            const int cbp = wn * 48 + j * 16 + fr;
            const int pan = (cbp >= 96) ? 1 : 0;
            const int rb = cbp - pan * 96;
            fb[j] = *reinterpret_cast<const bf16x8*>(b + 32768 + pan * 6144 + rb * 64 + ((s4 ^ ((rb >> 1) & 3)) << 4));
        }
        #pragma unroll
        for (int p = 0; p < 4; ++p) {
            bf16x8 fh[2], fl[2];
            #pragma unroll
            for (int f = 0; f < 2; ++f) {
                const int rl = p * 32 + f * 16 + fr;
                const int off = wm * 8192 + rl * 64 + ((s4 ^ ((rl >> 1) & 3)) << 4);
                fh[f] = *reinterpret_cast<const bf16x8*>(b + off);
                fl[f] = *reinterpret_cast<const bf16x8*>(b + 16384 + off);
            }
            __builtin_amdgcn_s_setprio(1);
            #pragma unroll
            for (int f = 0; f < 2; ++f)
                #pragma unroll
                for (int j = 0; j < 3; ++j) {
                    acc[p * 2 + f][j] = __builtin_amdgcn_mfma_f32_16x16x32_bf16(fh[f], fb[j], acc[p * 2 + f][j], 0, 0, 0);
                    acc[p * 2 + f][j] = __builtin_amdgcn_mfma_f32_16x16x32_bf16(fl[f], fb[j], acc[p * 2 + f][j], 0, 0, 0);
                }
            __builtin_amdgcn_s_setprio(0);
        }
        if (t + 2 < 128) {
            if (w < 4) asm volatile("s_waitcnt vmcnt(6)" ::: "memory");
            else       asm volatile("s_waitcnt vmcnt(5)" ::: "memory");
        } else {
            asm volatile("s_waitcnt vmcnt(0)" ::: "memory");
        }
        __builtin_amdgcn_s_barrier();
        __builtin_amdgcn_sched_barrier(0);
        if (++cur == 3) cur = 0;
    }

    const int r0 = by * 256 + wm * 128 + s4 * 4;
    const int c0 = bx * 192 + wn * 48 + fr;
    #pragma unroll
    for (int ri = 0; ri < 8; ++ri)
        #pragma unroll
        for (int j = 0; j < 3; ++j) {
            const int col = c0 + j * 16;
            #pragma unroll
            for (int rr = 0; rr < 4; ++rr) {
                const int row = r0 + ri * 16 + rr;
                if (col < 4096)      xq[(size_t)row * 4096 + col] = acc[ri][j][rr];
                else if (col < 5120) xk[(size_t)row * 1024 + (col - 4096)] = acc[ri][j][rr];
                else                 xv[(size_t)row * 1024 + (col - 5120)] = acc[ri][j][rr];
            }
        }
}

// ---------------- Output GEMM: 256x128 tile, same pipeline ----------------
__global__ __launch_bounds__(512) void gemm_out4(const uint16_t* __restrict__ aoh,
                                                 const uint16_t* __restrict__ aol,
                                                 const uint16_t* __restrict__ woh,
                                                 float* __restrict__ out)
{
    __shared__ char lds[3][40960];   // Ah 16K | Al 16K | Bh 8K

    const int bid = blockIdx.x;
    const int swz = (bid & 7) * 32 + (bid >> 3);
    const int by = swz >> 5;    // 0..7
    const int bx = swz & 31;    // 0..31
    const int tid = threadIdx.x;
    const int w = tid >> 6, lane = tid & 63;
    const int wm = w >> 2, wn = w & 3;
    const int fr = lane & 15, s4 = lane >> 4;

    const uint16_t* sp[5];
    int dof[5];
    #pragma unroll
    for (int i = 0; i < 5; ++i) {
        const int c = w + 8 * i;
        dof[i] = c * 1024;
        if (i < 4) {
            const uint16_t* base = (c < 16) ? aoh : aol;
            const int cc = c & 15;
            sp[i] = base + (size_t)(2 * by + (cc >> 3)) * 524288 + (cc & 7) * 512 + lane * 8;
        } else {
            sp[i] = woh + (size_t)bx * 524288 + (c - 32) * 512 + lane * 8;
        }
    }

    f32x4 acc[8][2] = {};

    #pragma unroll
    for (int i = 0; i < 5; ++i)
        __builtin_amdgcn_global_load_lds(
            (const __attribute__((address_space(1))) void*)(sp[i]),
            (__attribute__((address_space(3))) void*)(&lds[0][0] + dof[i]), 16, 0, 0);
    #pragma unroll
    for (int i = 0; i < 5; ++i)
        __builtin_amdgcn_global_load_lds(
            (const __attribute__((address_space(1))) void*)(sp[i] + 4096),
            (__attribute__((address_space(3))) void*)(&lds[1][0] + dof[i]), 16, 0, 0);
    asm volatile("s_waitcnt vmcnt(5)" ::: "memory");
    __builtin_amdgcn_s_barrier();
    __builtin_amdgcn_sched_barrier(0);

    int cur = 0;
    for (int t = 0; t < 128; ++t) {
        if (t + 2 < 128) {
            int nb = cur + 2; if (nb >= 3) nb -= 3;
            #pragma unroll
            for (int i = 0; i < 5; ++i)
                __builtin_amdgcn_global_load_lds(
                    (const __attribute__((address_space(1))) void*)(sp[i] + (size_t)(t + 2) * 4096),
                    (__attribute__((address_space(3))) void*)(&lds[nb][0] + dof[i]), 16, 0, 0);
        }
        const char* b = &lds[cur][0];

        bf16x8 fb[2];
        #pragma unroll
        for (int j = 0; j < 2; ++j) {
            const int cbp = wn * 32 + j * 16 + fr;
            fb[j] = *reinterpret_cast<const bf16x8*>(b + 32768 + cbp * 64 + ((s4 ^ ((cbp >> 1) & 3)) << 4));
        }
        #pragma unroll
        for (int p = 0; p < 4; ++p) {
            bf16x8 fh[2], fl[2];
            #pragma unroll
            for (int f = 0; f < 2; ++f) {
                const int rl = p * 32 + f * 16 + fr;
                const int off = wm * 8192 + rl * 64 + ((s4 ^ ((rl >> 1) & 3)) << 4);
                fh[f] = *reinterpret_cast<const bf16x8*>(b + off);
                fl[f] = *reinterpret_cast<const bf16x8*>(b + 16384 + off);
            }
            __builtin_amdgcn_s_setprio(1);
            #pragma unroll
            for (int f = 0; f < 2; ++f)
                #pragma unroll
                for (int j = 0; j < 2; ++j) {
                    acc[p * 2 + f][j] = __builtin_amdgcn_mfma_f32_16x16x32_bf16(fh[f], fb[j], acc[p * 2 + f][j], 0, 0, 0);
                    acc[p * 2 + f][j] = __builtin_amdgcn_mfma_f32_16x16x32_bf16(fl[f], fb[j], acc[p * 2 + f][j], 0, 0, 0);
                }
            __builtin_amdgcn_s_setprio(0);
        }
        if (t + 2 < 128) asm volatile("s_waitcnt vmcnt(5)" ::: "memory");
        else             asm volatile("s_waitcnt vmcnt(0)" ::: "memory");
        __builtin_amdgcn_s_barrier();
        __builtin_amdgcn_sched_barrier(0);
        if (++cur == 3) cur = 0;
    }

    const int r0 = by * 256 + wm * 128 + s4 * 4;
    const int c0 = bx * 128 + wn * 32 + fr;
    #pragma unroll
    for (int ri = 0; ri < 8; ++ri)
        #pragma unroll
        for (int j = 0; j < 2; ++j)
            #pragma unroll
            for (int rr = 0; rr < 4; ++rr)
                out[(size_t)(r0 + ri * 16 + rr) * 4096 + c0 + j * 16] = acc[ri][j][rr];
}

// ---------------- RoPE in place; Q additionally scaled by 1/sqrt(128) ----------------
__global__ __launch_bounds__(256) void rope_k(float* __restrict__ xq, float* __restrict__ xk)
{
    const int idx = blockIdx.x * 256 + threadIdx.x;
    const int TOTQ = 2048 * 32 * 64;
    int s, j;
    float* base;
    bool isq = idx < TOTQ;
    if (isq) {
        s = idx >> 11;
        const int rem = idx & 2047;
        j = rem & 63;
        base = xq + (size_t)s * 4096 + (rem >> 6) * 128 + 2 * j;
    } else {
        const int i2 = idx - TOTQ;
        s = i2 >> 9;
        const int rem = i2 & 511;
        j = rem & 63;
        base = xk + (size_t)s * 1024 + (rem >> 6) * 128 + 2 * j;
    }
    const float invf = exp2f(-(float)j * (13.287712379549449f / 64.0f));
    const float ang = (float)s * invf;
    float sn, cs;
    sincosf(ang, &sn, &cs);
    float2 v = *reinterpret_cast<float2*>(base);
    float2 r;
    r.x = v.x * cs - v.y * sn;
    r.y = v.x * sn + v.y * cs;
    if (isq) { r.x *= 0.08838834764831845f; r.y *= 0.08838834764831845f; }
    *reinterpret_cast<float2*>(base) = r;
}

// ---------------- Convert roped K (hi+lo) and raw V (hi only) to blocked+swizzled bf16 tiles ----------------
// Tile = 12288 uint16 (24 KB): Kh[32 kv][128 d] at 0, Kl at 4096, Vth[128 d][32 kv] at 8192.
__global__ __launch_bounds__(256) void conv_kv(const float* __restrict__ xk,
                                               const float* __restrict__ xv,
                                               uint16_t* __restrict__ kvg)
{
    __shared__ float V[32][129];
    const int t = blockIdx.x;
    const int h = blockIdx.y;
    const int tid = threadIdx.x;
    uint16_t* tile = kvg + ((size_t)(h * 64 + t)) * 12288;

    #pragma unroll
    for (int i = 0; i < 4; ++i) {
        int v = i * 256 + tid;
        int row = v >> 5, c4 = (v & 31) * 4;
        *reinterpret_cast<float4*>(&V[row][c4]) =
            *reinterpret_cast<const float4*>(&xv[(size_t)(t * 32 + row) * 1024 + h * 128 + c4]);
    }

    {
        const int r = tid >> 3;
        const int d0 = (tid & 7) * 16;
        float f[16];
        const float* kr = &xk[(size_t)(t * 32 + r) * 1024 + h * 128 + d0];
        *reinterpret_cast<float4*>(&f[0])  = *reinterpret_cast<const float4*>(kr);
        *reinterpret_cast<float4*>(&f[4])  = *reinterpret_cast<const float4*>(kr + 4);
        *reinterpret_cast<float4*>(&f[8])  = *reinterpret_cast<const float4*>(kr + 8);
        *reinterpret_cast<float4*>(&f[12]) = *reinterpret_cast<const float4*>(kr + 12);
        #pragma unroll
        for (int cc = 0; cc < 2; ++cc) {
            bf16x8 hv, lv;
            #pragma unroll
            for (int e = 0; e < 8; ++e) {
                float x = f[cc * 8 + e];
                bf16_t hb = (bf16_t)x;
                hv[e] = hb;
                lv[e] = (bf16_t)(x - (float)hb);
            }
            const int c = (d0 >> 3) + cc;
            const int pos = r * 128 + ((c ^ (r & 15)) << 3);
            *reinterpret_cast<bf16x8*>(&tile[pos]) = hv;
            *reinterpret_cast<bf16x8*>(&tile[4096 + pos]) = lv;
        }
    }
    __syncthreads();
    {
        const int d = tid >> 1;
        const int k0 = (tid & 1) * 16;
        float g[16];
        #pragma unroll
        for (int j = 0; j < 16; ++j) g[j] = V[k0 + j][d];
        #pragma unroll
        for (int cc = 0; cc < 2; ++cc) {
            bf16x8 hv;
            #pragma unroll
            for (int e = 0; e < 8; ++e) hv[e] = (bf16_t)g[cc * 8 + e];
            const int c = (k0 >> 3) + cc;
            const int pos = d * 32 + ((c ^ (d & 3)) << 3);
            *reinterpret_cast<bf16x8*>(&tile[8192 + pos]) = hv;
        }
    }
}

// ---------------- MFMA flash attention (2-pass QK, 1-pass PV, defer-max, fused packed epilogue) ----------------
__device__ __forceinline__ uint cvtpk(float lo, float hi) {
    uint r;
    asm("v_cvt_pk_bf16_f32 %0, %1, %2" : "=v"(r) : "v"(lo), "v"(hi));
    return r;
}
__device__ __forceinline__ void permswap(uint& a, uint& b) {
    asm("v_permlane32_swap_b32 %0, %1" : "+v"(a), "+v"(b));
}
__device__ __forceinline__ bf16x8 pack4(uint w0, uint w1, uint w2, uint w3) {
    union { uint u[4]; bf16x8 v; } t;
    t.u[0] = w0; t.u[1] = w1; t.u[2] = w2; t.u[3] = w3;
    return t.v;
}

__global__ __launch_bounds__(512, 2) void attn_mfma(const float* __restrict__ xq,
                                                    const uint16_t* __restrict__ kvg,
                                                    uint16_t* __restrict__ aoh,
                                                    uint16_t* __restrict__ aol)
{
    __shared__ char lds[2][24576];

    const int b = blockIdx.x;
    const int kvh = b & 7;
    const int r = b >> 3;
    const int h = kvh * 4 + (r & 3);
    const int q0 = (r >> 2) * 256;
    const int tid = threadIdx.x;
    const int w = tid >> 6;
    const int lane = tid & 63;
    const int ln31 = lane & 31;
    const int hi = lane >> 5;

    const int q = q0 + w * 32 + ln31;
    const float* qrow = xq + (size_t)q * 4096 + h * 128;
    bf16x8 Qh[8];
    #pragma unroll
    for (int ks = 0; ks < 8; ++ks) {
        float f[8];
        *reinterpret_cast<float4*>(&f[0]) = *reinterpret_cast<const float4*>(qrow + ks * 16 + hi * 8);
        *reinterpret_cast<float4*>(&f[4]) = *reinterpret_cast<const float4*>(qrow + ks * 16 + hi * 8 + 4);
        #pragma unroll
        for (int e = 0; e < 8; ++e) Qh[ks][e] = (bf16_t)f[e];
    }

    const char* gkv = (const char*)kvg + (size_t)kvh * 64 * 24576;

    f32x16 oacc[4] = {{}, {}, {}, {}};
    float m = -3.0e38f, l = 0.f;

    {
        #pragma unroll
        for (int i = 0; i < 3; ++i) {
            const int chunk = i * 8 + w;
            __builtin_amdgcn_global_load_lds(
                (const __attribute__((address_space(1))) void*)(gkv + chunk * 1024 + lane * 16),
                (__attribute__((address_space(3))) void*)(&lds[0][chunk * 1024]),
                16, 0, 0);
        }
    }

    for (int t = 0; t < 64; ++t) {
        __syncthreads();
        if (t + 1 < 64) {
            const char* g = gkv + (size_t)(t + 1) * 24576;
            const int buf = (t + 1) & 1;
            #pragma unroll
            for (int i = 0; i < 3; ++i) {
                const int chunk = i * 8 + w;
                __builtin_amdgcn_global_load_lds(
                    (const __attribute__((address_space(1))) void*)(g + chunk * 1024 + lane * 16),
                    (__attribute__((address_space(3))) void*)(&lds[buf][chunk * 1024]),
                    16, 0, 0);
            }
        }
        const int cur = t & 1;
        const char* Kh = lds[cur];
        const char* Kl = lds[cur] + 8192;
        const char* Vh = lds[cur] + 16384;

        f32x16 s = {};
        __builtin_amdgcn_s_setprio(1);
        #pragma unroll
        for (int ks = 0; ks < 8; ++ks) {
            const int byt = ln31 * 256 + ((ks * 32 + hi * 16) ^ ((ln31 & 15) << 4));
            bf16x8 ah = *reinterpret_cast<const bf16x8*>(Kh + byt);
            bf16x8 al = *reinterpret_cast<const bf16x8*>(Kl + byt);
            s = __builtin_amdgcn_mfma_f32_32x32x16_bf16(ah, Qh[ks], s, 0, 0, 0);
            s = __builtin_amdgcn_mfma_f32_32x32x16_bf16(al, Qh[ks], s, 0, 0, 0);
        }
        __builtin_amdgcn_s_setprio(0);

        float pmax = s[0];
        #pragma unroll
        for (int jj = 1; jj < 16; ++jj) pmax = fmaxf(pmax, s[jj]);
        pmax = fmaxf(pmax, __shfl_xor(pmax, 32));
        if (!__all(pmax - m <= 8.0f)) {
            const float mnew = fmaxf(m, pmax);
            const float corr = __expf(m - mnew);
            l *= corr;
            #pragma unroll
            for (int dt = 0; dt < 4; ++dt) oacc[dt] *= corr;
            m = mnew;
        }
        float psum = 0.f;
        #pragma unroll
        for (int jj = 0; jj < 16; ++jj) {
            float pv = __expf(s[jj] - m);
            s[jj] = pv;
            psum += pv;
        }
        psum += __shfl_xor(psum, 32);
        l += psum;

        #pragma unroll
        for (int ks = 0; ks < 2; ++ks) {
            const int b0 = ks * 8;
            uint wa = cvtpk(s[b0 + 0], s[b0 + 1]);
            uint wb = cvtpk(s[b0 + 2], s[b0 + 3]);
            uint wc = cvtpk(s[b0 + 4], s[b0 + 5]);
            uint wd = cvtpk(s[b0 + 6], s[b0 + 7]);
            permswap(wa, wc); permswap(wb, wd);
            bf16x8 Pf = pack4(wa, wb, wc, wd);
            __builtin_amdgcn_s_setprio(1);
            #pragma unroll
            for (int dt = 0; dt < 4; ++dt) {
                const int row = dt * 32 + ln31;
                const int byt = row * 64 + ((ks * 32 + hi * 16) ^ ((row & 3) << 4));
                bf16x8 vh = *reinterpret_cast<const bf16x8*>(Vh + byt);
                oacc[dt] = __builtin_amdgcn_mfma_f32_32x32x16_bf16(vh, Pf, oacc[dt], 0, 0, 0);
            }
            __builtin_amdgcn_s_setprio(0);
        }
    }

    const float invl = 1.0f / l;
    const int p   = q >> 7;
    const int rr_ = q & 127;
    const int rsw = (rr_ >> 1) & 3;
    #pragma unroll
    for (int dt = 0; dt < 4; ++dt) {
        const int kb = h * 4 + dt;
        uint16_t* bh = aoh + ((size_t)p * 128 + kb) * 4096;
        uint16_t* bl = aol + ((size_t)p * 128 + kb) * 4096;
        #pragma unroll
        for (int g4 = 0; g4 < 4; ++g4) {
            bf16x4 hv, lv;
            #pragma unroll
            for (int e = 0; e < 4; ++e) {
                float v = oacc[dt][g4 * 4 + e] * invl;
                bf16_t hb = (bf16_t)v;
                hv[e] = hb;
                lv[e] = (bf16_t)(v - (float)hb);
            }
            const int pos = rr_ * 32 + ((g4 ^ rsw) << 3) + 4 * hi;
            *reinterpret_cast<bf16x4*>(&bh[pos]) = hv;
            *reinterpret_cast<bf16x4*>(&bl[pos]) = lv;
        }
    }
}

extern "C" void kernel_launch(void* const* d_in, const int* in_sizes, int n_in,
                              void* d_out, int out_size, void* d_ws, size_t ws_size,
                              hipStream_t stream)
{
    const float* x  = (const float*)d_in[0];
    const float* wq = (const float*)d_in[1];
    const float* wk = (const float*)d_in[2];
    const float* wv = (const float*)d_in[3];
    const float* wo = (const float*)d_in[4];
    float* out = (float*)d_out;

    float* ws = (float*)d_ws;
    // float-slot offsets (ws >= 218 MB, verified rounds 3-7)
    float*    xq   = ws;                           // [0, 8388608)
    uint16_t* kvg  = (uint16_t*)(ws + 8388608);    // [8388608, 11534336)
    float*    xk   = ws + 12582912;                // [12582912, 14680064)
    float*    xv   = ws + 14680064;                // [14680064, 16777216)
    uint16_t* aoh  = (uint16_t*)(ws + 12582912);   // reuses xk slot after conv_kv
    uint16_t* aol  = (uint16_t*)(ws + 16777216);
    uint16_t* xh   = (uint16_t*)(ws + 20971520);
    uint16_t* xl   = (uint16_t*)(ws + 25165824);
    uint16_t* wqkv = (uint16_t*)(ws + 29360128);   // 25.2M elems (96-col-panel combined pack)
    uint16_t* woh  = (uint16_t*)(ws + 41943040);   // 16.8M elems

    dim3 blk(256);
    repack_hl <<<dim3(128, 16), blk, 0, stream>>>(x, xh, xl);
    repack_w96<<<dim3(128, 64), blk, 0, stream>>>(wq, wk, wv, wqkv);
    gemm_qkv4 <<<dim3(256), dim3(512), 0, stream>>>(xh, xl, wqkv, xq, xk, xv);
    repack_h  <<<dim3(128, 32), blk, 0, stream>>>(wo, woh);
    rope_k    <<<dim3(20480), blk, 0, stream>>>(xq, xk);
    conv_kv   <<<dim3(64, 8), blk, 0, stream>>>(xk, xv, kvg);
    attn_mfma <<<dim3(256), dim3(512), 0, stream>>>(xq, kvg, aoh, aol);
    gemm_out4 <<<dim3(256), dim3(512), 0, stream>>>(aoh, aol, woh, out);
}